// Round 2
// 665.972 us; speedup vs baseline: 1.3146x; 1.3146x over previous
//
#include <hip/hip_runtime.h>
#include <stdint.h>

// ---------------------------------------------------------------------------
// EvaLinearAttention on MI355X (gfx950).
// B=8, N=4096, C=768, H=12, D=64, npt=1. I/O fp32; GEMMs bf16 MFMA;
// attention middle: fp32 vector implementation.
// R1 change: pass_a was occupancy-starved (96 blocks, 4.5% occupancy,
// 310us). Split token dim 16-way -> 1536 blocks, LDS cross-wave merge,
// contention-free partials + tiny reduce kernel.
// (R1 bench was a broker timeout; re-submitting unchanged for measurement.)
// ---------------------------------------------------------------------------

typedef __attribute__((ext_vector_type(8))) short short8;
typedef __attribute__((ext_vector_type(4))) float floatx4;

#define SPLIT_A 16
#define TILES_PER_BLK (32 / SPLIT_A)

__device__ __forceinline__ float b2f(unsigned short u) {
  union { unsigned int i; float f; } v; v.i = ((unsigned int)u) << 16; return v.f;
}
__device__ __forceinline__ unsigned short f2b(float f) {
  union { float f; unsigned int i; } v; v.f = f;
  unsigned int i = v.i;
  unsigned int r = (i + 0x7FFFu + ((i >> 16) & 1u)) >> 16;  // RNE
  return (unsigned short)r;
}
__device__ __forceinline__ void unpack2(unsigned int u, float& a, float& b) {
  union { unsigned int i; float f; } x, y;
  x.i = u << 16; y.i = u & 0xFFFF0000u;
  a = x.f; b = y.f;
}

__device__ __forceinline__ void stage16(const void* g, void* l) {
#if defined(__has_builtin) && __has_builtin(__builtin_amdgcn_global_load_lds)
  __builtin_amdgcn_global_load_lds(
      (const __attribute__((address_space(1))) unsigned int*)g,
      (__attribute__((address_space(3))) unsigned int*)l, 16, 0, 0);
#else
  *(uint4*)l = *(const uint4*)g;
#endif
}

// ---------------------------------------------------------------------------
__global__ __launch_bounds__(256) void f32_to_bf16(
    const float* __restrict__ in, unsigned short* __restrict__ out, int n) {
  const int i = (blockIdx.x * 256 + threadIdx.x) * 8;
  if (i + 7 < n) {
    float4 a = *(const float4*)(in + i);
    float4 b = *(const float4*)(in + i + 4);
    unsigned short tmp[8] = {f2b(a.x), f2b(a.y), f2b(a.z), f2b(a.w),
                             f2b(b.x), f2b(b.y), f2b(b.z), f2b(b.w)};
    *(uint4*)(out + i) = *(uint4*)tmp;
  }
}

// ---------------------------------------------------------------------------
// bf16 GEMM, B^T: Out[M,Nout] = A[M,K] * W[Nout,K]^T + bias. (m97 pattern)
// ---------------------------------------------------------------------------
template <int OUT_BF16>
__global__ __launch_bounds__(256) void gemm_bt(
    const unsigned short* __restrict__ A, const unsigned short* __restrict__ W,
    const float* __restrict__ bias, void* __restrict__ Out,
    int M, int K, int Nout) {
  __shared__ __align__(16) unsigned short sA[128 * 32];
  __shared__ __align__(16) unsigned short sB[128 * 32];
  const int bn = blockIdx.x, bm = blockIdx.y;
  const int t = threadIdx.x;
  const int lane = t & 63, wave = t >> 6;
  const int wm = (wave >> 1) * 64, wn = (wave & 1) * 64;
  const int lr = t >> 2;
  const int lc = (t & 3) * 8;
  const size_t baseA = (size_t)(bm * 128 + lr) * K + lc;
  const size_t baseB = (size_t)(bn * 128 + lr) * K + lc;
  floatx4 acc[4][4] = {};

  const int mr = lane & 15, kq = (lane >> 4) * 8;
  for (int k0 = 0; k0 < K; k0 += 32) {
    stage16(A + baseA + k0, &sA[t * 8]);
    stage16(A + baseA + (size_t)64 * K + k0, &sA[2048 + t * 8]);
    stage16(W + baseB + k0, &sB[t * 8]);
    stage16(W + baseB + (size_t)64 * K + k0, &sB[2048 + t * 8]);
    __syncthreads();
    short8 af[4], bfr[4];
#pragma unroll
    for (int i = 0; i < 4; i++) af[i] = *(const short8*)&sA[(wm + i * 16 + mr) * 32 + kq];
#pragma unroll
    for (int j = 0; j < 4; j++) bfr[j] = *(const short8*)&sB[(wn + j * 16 + mr) * 32 + kq];
#pragma unroll
    for (int i = 0; i < 4; i++)
#pragma unroll
      for (int j = 0; j < 4; j++)
        acc[i][j] = __builtin_amdgcn_mfma_f32_16x16x32_bf16(af[i], bfr[j], acc[i][j], 0, 0, 0);
    __syncthreads();
  }

  const int mr4 = (lane >> 4) * 4, nc = lane & 15;
#pragma unroll
  for (int j = 0; j < 4; j++) {
    const int gc = bn * 128 + wn + j * 16 + nc;
    const float bv = bias[gc];
#pragma unroll
    for (int i = 0; i < 4; i++) {
      const int gr0 = bm * 128 + wm + i * 16 + mr4;
#pragma unroll
      for (int r = 0; r < 4; r++) {
        float v = acc[i][j][r] + bv;
        if (OUT_BF16)
          ((unsigned short*)Out)[(size_t)(gr0 + r) * Nout + gc] = f2b(v);
        else
          ((float*)Out)[(size_t)(gr0 + r) * Nout + gc] = v;
      }
    }
  }
}

// ---------------------------------------------------------------------------
// pass_a (split fp32): one block per (bh, split); split handles TILES_PER_BLK
// tiles of 128 tokens. Threads t<128 compute phi_k (fp32, full 64-dim softmax
// in regs) + stage v (bf16 raw). All 4 waves accumulate: wave w handles
// tokens [w*32,w*32+32) of the tile; lane owns d-block dg*4 x e-block eg*16.
// Cross-wave merge via LDS (reusing sphi, stride-33 padded), then plain
// (non-atomic) float4 stores to a per-(bh,split) partial slice of kvP.
// reduce_kv folds the SPLIT_A partials into kvG.
// ---------------------------------------------------------------------------
__global__ __launch_bounds__(256) void pass_a(
    const unsigned short* __restrict__ qkv, const float* __restrict__ rope,
    float* __restrict__ kvP) {
  __shared__ float sphi[128 * 65];               // 33,280 B (pad 65: no conflicts)
  __shared__ __align__(16) unsigned short sv[128 * 64];  // 16,384 B
  const int bh = blockIdx.x, b = bh / 12, h = bh % 12;
  const int sp = blockIdx.y;
  const int t = threadIdx.x;
  const int lane = t & 63, wave = t >> 6;
  const int dg = lane >> 2;   // d = dg*4 + i
  const int eg = lane & 3;    // e = eg*16 + j
  float acc[4][16] = {};
  float ks4[4] = {};

  const int tile0 = sp * TILES_PER_BLK;
  for (int tile = tile0; tile < tile0 + TILES_PER_BLK; tile++) {
    __syncthreads();
    if (t < 128) {
      const int n = tile * 128 + t;
      const size_t rowb = (size_t)(b * 4096 + n) * 2304;
      const unsigned short* kp = qkv + rowb + 768 + h * 64;
      float kk[64];
#pragma unroll
      for (int c = 0; c < 8; c++) {
        uint4 u = *(const uint4*)(kp + c * 8);
        unpack2(u.x, kk[c * 8 + 0], kk[c * 8 + 1]);
        unpack2(u.y, kk[c * 8 + 2], kk[c * 8 + 3]);
        unpack2(u.z, kk[c * 8 + 4], kk[c * 8 + 5]);
        unpack2(u.w, kk[c * 8 + 6], kk[c * 8 + 7]);
      }
      if (n > 0) {
        const float* rp = rope + (size_t)(n - 1) * 128;
#pragma unroll
        for (int c = 0; c < 8; c++) {
          float sn[8], cs[8];
          *(float4*)&sn[0] = *(const float4*)(rp + c * 8);
          *(float4*)&sn[4] = *(const float4*)(rp + c * 8 + 4);
          *(float4*)&cs[0] = *(const float4*)(rp + 64 + c * 8);
          *(float4*)&cs[4] = *(const float4*)(rp + 64 + c * 8 + 4);
#pragma unroll
          for (int i = 0; i < 4; i++) {
            float e = kk[c * 8 + 2 * i], o = kk[c * 8 + 2 * i + 1];
            kk[c * 8 + 2 * i] = e * cs[2 * i] - o * sn[2 * i];
            kk[c * 8 + 2 * i + 1] = o * cs[2 * i + 1] + e * sn[2 * i + 1];
          }
        }
      }
      float mx = kk[0];
#pragma unroll
      for (int i = 1; i < 64; i++) mx = fmaxf(mx, kk[i]);
      float s = 0.f;
#pragma unroll
      for (int i = 0; i < 64; i++) { float e = __expf(kk[i] - mx); kk[i] = e; s += e; }
      const float inv = 1.f / s;
#pragma unroll
      for (int d = 0; d < 64; d++) sphi[t * 65 + d] = kk[d] * inv;
      const unsigned short* vp = qkv + rowb + 1536 + h * 64;
#pragma unroll
      for (int c = 0; c < 8; c++)
        *(uint4*)&sv[t * 64 + c * 8] = *(const uint4*)(vp + c * 8);
    }
    __syncthreads();
    const int n0 = wave * 32;
    for (int nn = n0; nn < n0 + 32; nn++) {
      float p[4];
#pragma unroll
      for (int i = 0; i < 4; i++) p[i] = sphi[nn * 65 + dg * 4 + i];
#pragma unroll
      for (int i = 0; i < 4; i++) ks4[i] += p[i];
      float vv[16];
      {
        uint4 u0 = *(const uint4*)&sv[nn * 64 + eg * 16];
        uint4 u1 = *(const uint4*)&sv[nn * 64 + eg * 16 + 8];
        unpack2(u0.x, vv[0], vv[1]);   unpack2(u0.y, vv[2], vv[3]);
        unpack2(u0.z, vv[4], vv[5]);   unpack2(u0.w, vv[6], vv[7]);
        unpack2(u1.x, vv[8], vv[9]);   unpack2(u1.y, vv[10], vv[11]);
        unpack2(u1.z, vv[12], vv[13]); unpack2(u1.w, vv[14], vv[15]);
      }
#pragma unroll
      for (int i = 0; i < 4; i++)
#pragma unroll
        for (int j = 0; j < 16; j++)
          acc[i][j] += p[i] * vv[j];
    }
  }

  // ---- cross-wave merge via LDS (reuse sphi as [192][33] f32 scratch) ----
  __syncthreads();
  float* sred = sphi;
  float* o = kvP + ((size_t)bh * SPLIT_A + sp) * 4160;
#pragma unroll
  for (int half = 0; half < 2; half++) {
    if (wave != 0) {
      float* row = &sred[((wave - 1) * 64 + lane) * 33];
#pragma unroll
      for (int i = 0; i < 4; i++)
#pragma unroll
        for (int jj = 0; jj < 8; jj++) row[i * 8 + jj] = acc[i][half * 8 + jj];
    }
    __syncthreads();
    if (wave == 0) {
#pragma unroll
      for (int jj = 0; jj < 8; jj++) {
        float4 s4;
        float sv4[4];
#pragma unroll
        for (int i = 0; i < 4; i++) {
          float s = acc[i][half * 8 + jj];
#pragma unroll
          for (int w = 0; w < 3; w++) s += sred[(w * 64 + lane) * 33 + i * 8 + jj];
          sv4[i] = s;
        }
        s4.x = sv4[0]; s4.y = sv4[1]; s4.z = sv4[2]; s4.w = sv4[3];
        const int e = eg * 16 + half * 8 + jj;
        *(float4*)&o[e * 64 + dg * 4] = s4;
      }
    }
    __syncthreads();
  }
  // ---- ksum merge ----
  if (wave != 0) {
#pragma unroll
    for (int i = 0; i < 4; i++) sred[((wave - 1) * 64 + lane) * 5 + i] = ks4[i];
  }
  __syncthreads();
  if (wave == 0 && eg == 0) {
    float4 s4;
    float sv4[4];
#pragma unroll
    for (int i = 0; i < 4; i++) {
      float s = ks4[i];
#pragma unroll
      for (int w = 0; w < 3; w++) s += sred[(w * 64 + lane) * 5 + i];
      sv4[i] = s;
    }
    s4.x = sv4[0]; s4.y = sv4[1]; s4.z = sv4[2]; s4.w = sv4[3];
    *(float4*)&o[4096 + dg * 4] = s4;
  }
}

// ---------------------------------------------------------------------------
// reduce_kv: kvG[bh][r] = sum_{sp<SPLIT_A} kvP[bh][sp][r]. 96*4160 outputs.
// ---------------------------------------------------------------------------
__global__ __launch_bounds__(256) void reduce_kv(
    const float* __restrict__ kvP, float* __restrict__ kvG) {
  const int i = blockIdx.x * 256 + threadIdx.x;
  if (i >= 96 * 4160) return;
  const int bh = i / 4160, r = i - bh * 4160;
  const float* p = kvP + (size_t)bh * SPLIT_A * 4160 + r;
  float s = 0.f;
#pragma unroll
  for (int sp = 0; sp < SPLIT_A; sp++) s += p[(size_t)sp * 4160];
  kvG[i] = s;
}

// ---------------------------------------------------------------------------
// pass_b (simple): one thread per token. phi_q fp32 in regs; kv staged to
// LDS as bf16 [e][d]; out[n,e] = (sum_d phi_q[d]*kv[d,e]) / (z+eps), bf16.
// All lanes read the same LDS address (broadcast, conflict-free).
// ---------------------------------------------------------------------------
__global__ __launch_bounds__(256) void pass_b(
    const unsigned short* __restrict__ qkv, const float* __restrict__ rope,
    const float* __restrict__ kvG, unsigned short* __restrict__ attn) {
  __shared__ __align__(16) unsigned short skvh[4096];  // [e][d] bf16
  __shared__ float sks[64];
  const int bh = blockIdx.x, b = bh / 12, h = bh % 12;
  const int t = threadIdx.x;
  const float* kvb = kvG + (size_t)bh * 4160;
  {
    const float* src = kvb + t * 16;
    unsigned short tmp[16];
#pragma unroll
    for (int i = 0; i < 16; i++) tmp[i] = f2b(src[i]);
    *(uint4*)&skvh[t * 16] = *(uint4*)&tmp[0];
    *(uint4*)&skvh[t * 16 + 8] = *(uint4*)&tmp[8];
  }
  if (t < 64) sks[t] = kvb[4096 + t];
  __syncthreads();

  const int n = blockIdx.y * 256 + t;
  const size_t rowb = (size_t)(b * 4096 + n) * 2304;
  const unsigned short* qp = qkv + rowb + h * 64;
  float ph[64];
#pragma unroll
  for (int c = 0; c < 8; c++) {
    uint4 u = *(const uint4*)(qp + c * 8);
    unpack2(u.x, ph[c * 8 + 0], ph[c * 8 + 1]);
    unpack2(u.y, ph[c * 8 + 2], ph[c * 8 + 3]);
    unpack2(u.z, ph[c * 8 + 4], ph[c * 8 + 5]);
    unpack2(u.w, ph[c * 8 + 6], ph[c * 8 + 7]);
  }
  if (n > 0) {
    const float* rp = rope + (size_t)(n - 1) * 128;
#pragma unroll
    for (int c = 0; c < 8; c++) {
      float sn[8], cs[8];
      *(float4*)&sn[0] = *(const float4*)(rp + c * 8);
      *(float4*)&sn[4] = *(const float4*)(rp + c * 8 + 4);
      *(float4*)&cs[0] = *(const float4*)(rp + 64 + c * 8);
      *(float4*)&cs[4] = *(const float4*)(rp + 64 + c * 8 + 4);
#pragma unroll
      for (int i = 0; i < 4; i++) {
        float e = ph[c * 8 + 2 * i], o = ph[c * 8 + 2 * i + 1];
        ph[c * 8 + 2 * i] = e * cs[2 * i] - o * sn[2 * i];
        ph[c * 8 + 2 * i + 1] = o * cs[2 * i + 1] + e * sn[2 * i + 1];
      }
    }
  }
  float mx = ph[0];
#pragma unroll
  for (int i = 1; i < 64; i++) mx = fmaxf(mx, ph[i]);
  float s = 0.f;
#pragma unroll
  for (int i = 0; i < 64; i++) { float e = __expf(ph[i] - mx); ph[i] = e; s += e; }
  const float inv = 1.f / s;
  float z = 0.f;
#pragma unroll
  for (int i = 0; i < 64; i++) { ph[i] *= inv; z += ph[i] * sks[i]; }
  const float zi = 1.f / (z + 1e-5f);

  unsigned short* orow = attn + (size_t)(b * 4096 + n) * 768 + h * 64;
  unsigned short tmp8[8];
  for (int e = 0; e < 64; e++) {
    float acc = 0.f;
#pragma unroll
    for (int c = 0; c < 8; c++) {
      uint4 u = *(const uint4*)&skvh[e * 64 + c * 8];
      float f0, f1;
      unpack2(u.x, f0, f1); acc += ph[c * 8 + 0] * f0 + ph[c * 8 + 1] * f1;
      unpack2(u.y, f0, f1); acc += ph[c * 8 + 2] * f0 + ph[c * 8 + 3] * f1;
      unpack2(u.z, f0, f1); acc += ph[c * 8 + 4] * f0 + ph[c * 8 + 5] * f1;
      unpack2(u.w, f0, f1); acc += ph[c * 8 + 6] * f0 + ph[c * 8 + 7] * f1;
    }
    tmp8[e & 7] = f2b(acc * zi);
    if ((e & 7) == 7) *(uint4*)&orow[e - 7] = *(uint4*)&tmp8[0];
  }
}

// ---------------------------------------------------------------------------
// LayerNorm over C=768, in-place on bf16 buffer; gamma/beta fp32.
// ---------------------------------------------------------------------------
__global__ __launch_bounds__(256) void ln_kernel(
    unsigned short* __restrict__ buf, const float* __restrict__ g,
    const float* __restrict__ be) {
  const int row = blockIdx.x;
  const int t = threadIdx.x;
  unsigned short* p = buf + (size_t)row * 768;
  const float x0 = b2f(p[t]), x1 = b2f(p[t + 256]), x2 = b2f(p[t + 512]);
  float s = x0 + x1 + x2;
  float ss = x0 * x0 + x1 * x1 + x2 * x2;
#pragma unroll
  for (int m = 1; m < 64; m <<= 1) { s += __shfl_xor(s, m); ss += __shfl_xor(ss, m); }
  __shared__ float red[8];
  const int wave = t >> 6, lane = t & 63;
  if (lane == 0) { red[wave] = s; red[4 + wave] = ss; }
  __syncthreads();
  s = red[0] + red[1] + red[2] + red[3];
  ss = red[4] + red[5] + red[6] + red[7];
  const float mean = s * (1.f / 768.f);
  const float var = ss * (1.f / 768.f) - mean * mean;
  const float rsq = rsqrtf(var + 1e-5f);
  p[t] = f2b((x0 - mean) * rsq * g[t] + be[t]);
  p[t + 256] = f2b((x1 - mean) * rsq * g[t + 256] + be[t + 256]);
  p[t + 512] = f2b((x2 - mean) * rsq * g[t + 512] + be[t + 512]);
}

__global__ void setup_bias(const float* qb, const float* vb, const float* pb,
                           float* qkvb, float* projb) {
  const int i = blockIdx.x * 256 + threadIdx.x;
  if (i < 2304) qkvb[i] = (i < 768) ? qb[i] : (i >= 1536 ? vb[i - 1536] : 0.f);
  if (i < 768) projb[i] = pb[i];
}

// ---------------------------------------------------------------------------
extern "C" void kernel_launch(void* const* d_in, const int* in_sizes, int n_in,
                              void* d_out, int out_size, void* d_ws, size_t ws_size,
                              hipStream_t stream) {
  (void)in_sizes; (void)n_in; (void)out_size; (void)ws_size;
  const float* x      = (const float*)d_in[0];
  const float* rope   = (const float*)d_in[1];
  const float* qkv_w  = (const float*)d_in[2];
  const float* q_bias = (const float*)d_in[3];
  const float* v_bias = (const float*)d_in[4];
  const float* norm_g = (const float*)d_in[5];
  const float* norm_b = (const float*)d_in[6];
  const float* proj_w = (const float*)d_in[7];
  const float* proj_b = (const float*)d_in[8];

  char* ws = (char*)d_ws;
  unsigned short* qkv  = (unsigned short*)ws;                // 150,994,944 B
  unsigned short* attn = (unsigned short*)(ws + 150994944);  //  50,331,648 B
  unsigned short* xbf  = attn;  // aliased: x_bf16 dead before attn is written
  float* kvP   = (float*)(ws + 150994944);  // aliased: partials dead before attn
  float* kvG   = (float*)(ws + 201326592);                   //   1,597,440 B
  float* qkvb  = (float*)(ws + 202924032);
  float* projb = (float*)(ws + 202933248);
  unsigned short* wbf  = (unsigned short*)(ws + 202936320);  //   3,538,944 B
  unsigned short* pwbf = (unsigned short*)(ws + 206475264);  //   1,179,648 B

  f32_to_bf16<<<dim3(12288), dim3(256), 0, stream>>>(x, xbf, 25165824);
  f32_to_bf16<<<dim3(864), dim3(256), 0, stream>>>(qkv_w, wbf, 1769472);
  f32_to_bf16<<<dim3(288), dim3(256), 0, stream>>>(proj_w, pwbf, 589824);
  setup_bias<<<dim3(9), dim3(256), 0, stream>>>(q_bias, v_bias, proj_b, qkvb, projb);
  // qkv = x @ qkv_w^T + qkv_bias (M=32768, K=768, Nout=2304), bf16 out
  gemm_bt<1><<<dim3(18, 256), dim3(256), 0, stream>>>(xbf, wbf, qkvb, qkv, 32768, 768, 2304);
  // NOTE: xbf (== kvP region) is dead from here on.
  // kv / ksum partial reduction, 16-way token split (fp32, contention-free)
  pass_a<<<dim3(96, SPLIT_A), dim3(256), 0, stream>>>(qkv, rope, kvP);
  // fold partials into kvG
  reduce_kv<<<dim3(1560), dim3(256), 0, stream>>>(kvP, kvG);
  // attn = phi_q @ kv / (z + eps) (simple fp32 -> bf16); overwrites kvP region
  pass_b<<<dim3(96, 16), dim3(256), 0, stream>>>(qkv, rope, kvG, attn);
  // LayerNorm in-place
  ln_kernel<<<dim3(32768), dim3(256), 0, stream>>>(attn, norm_g, norm_b);
  // out = ln @ proj_w^T + proj_b (M=32768, K=768, Nout=768) -> d_out fp32
  gemm_bt<0><<<dim3(6, 256), dim3(256), 0, stream>>>(attn, pwbf, projb, d_out, 32768, 768, 768);
}

// Round 3
// 657.939 us; speedup vs baseline: 1.3307x; 1.0122x over previous
//
#include <hip/hip_runtime.h>
#include <stdint.h>

// ---------------------------------------------------------------------------
// EvaLinearAttention on MI355X (gfx950).
// B=8, N=4096, C=768, H=12, D=64, npt=1. I/O fp32; GEMMs bf16 MFMA;
// attention middle: fp32 vector implementation.
// R1: pass_a 16-way token split (310us -> off top-5). Total 875 -> 666us.
// R2: QKV GEMM is leader (190us, FETCH 250MB vs ~54 ideal = XCD L2 thrash).
//     Add bijective XCD-chunked blockIdx swizzle (T1) to both GEMMs:
//     1D grid, bn innermost, each XCD gets a contiguous bm-row chunk so
//     A panels are fetched once chip-wide and W stays L2-resident per XCD.
// ---------------------------------------------------------------------------

typedef __attribute__((ext_vector_type(8))) short short8;
typedef __attribute__((ext_vector_type(4))) float floatx4;

#define SPLIT_A 16
#define TILES_PER_BLK (32 / SPLIT_A)

__device__ __forceinline__ float b2f(unsigned short u) {
  union { unsigned int i; float f; } v; v.i = ((unsigned int)u) << 16; return v.f;
}
__device__ __forceinline__ unsigned short f2b(float f) {
  union { float f; unsigned int i; } v; v.f = f;
  unsigned int i = v.i;
  unsigned int r = (i + 0x7FFFu + ((i >> 16) & 1u)) >> 16;  // RNE
  return (unsigned short)r;
}
__device__ __forceinline__ void unpack2(unsigned int u, float& a, float& b) {
  union { unsigned int i; float f; } x, y;
  x.i = u << 16; y.i = u & 0xFFFF0000u;
  a = x.f; b = y.f;
}

__device__ __forceinline__ void stage16(const void* g, void* l) {
#if defined(__has_builtin) && __has_builtin(__builtin_amdgcn_global_load_lds)
  __builtin_amdgcn_global_load_lds(
      (const __attribute__((address_space(1))) unsigned int*)g,
      (__attribute__((address_space(3))) unsigned int*)l, 16, 0, 0);
#else
  *(uint4*)l = *(const uint4*)g;
#endif
}

// ---------------------------------------------------------------------------
__global__ __launch_bounds__(256) void f32_to_bf16(
    const float* __restrict__ in, unsigned short* __restrict__ out, int n) {
  const int i = (blockIdx.x * 256 + threadIdx.x) * 8;
  if (i + 7 < n) {
    float4 a = *(const float4*)(in + i);
    float4 b = *(const float4*)(in + i + 4);
    unsigned short tmp[8] = {f2b(a.x), f2b(a.y), f2b(a.z), f2b(a.w),
                             f2b(b.x), f2b(b.y), f2b(b.z), f2b(b.w)};
    *(uint4*)(out + i) = *(uint4*)tmp;
  }
}

// ---------------------------------------------------------------------------
// bf16 GEMM, B^T: Out[M,Nout] = A[M,K] * W[Nout,K]^T + bias. (m97 pattern)
// 1D grid, XCD-chunked swizzle (requires gridDim.x % 8 == 0); bn innermost
// within each XCD chunk so the A panel is reused across bn and W stays
// resident in the per-XCD L2.
// ---------------------------------------------------------------------------
template <int OUT_BF16>
__global__ __launch_bounds__(256) void gemm_bt(
    const unsigned short* __restrict__ A, const unsigned short* __restrict__ W,
    const float* __restrict__ bias, void* __restrict__ Out,
    int M, int K, int Nout, int nbn) {
  __shared__ __align__(16) unsigned short sA[128 * 32];
  __shared__ __align__(16) unsigned short sB[128 * 32];
  const int nwg = gridDim.x;
  const int orig = blockIdx.x;
  const int wg = (orig & 7) * (nwg >> 3) + (orig >> 3);  // bijective: nwg%8==0
  const int bm = wg / nbn;
  const int bn = wg - bm * nbn;
  const int t = threadIdx.x;
  const int lane = t & 63, wave = t >> 6;
  const int wm = (wave >> 1) * 64, wn = (wave & 1) * 64;
  const int lr = t >> 2;
  const int lc = (t & 3) * 8;
  const size_t baseA = (size_t)(bm * 128 + lr) * K + lc;
  const size_t baseB = (size_t)(bn * 128 + lr) * K + lc;
  floatx4 acc[4][4] = {};

  const int mr = lane & 15, kq = (lane >> 4) * 8;
  for (int k0 = 0; k0 < K; k0 += 32) {
    stage16(A + baseA + k0, &sA[t * 8]);
    stage16(A + baseA + (size_t)64 * K + k0, &sA[2048 + t * 8]);
    stage16(W + baseB + k0, &sB[t * 8]);
    stage16(W + baseB + (size_t)64 * K + k0, &sB[2048 + t * 8]);
    __syncthreads();
    short8 af[4], bfr[4];
#pragma unroll
    for (int i = 0; i < 4; i++) af[i] = *(const short8*)&sA[(wm + i * 16 + mr) * 32 + kq];
#pragma unroll
    for (int j = 0; j < 4; j++) bfr[j] = *(const short8*)&sB[(wn + j * 16 + mr) * 32 + kq];
#pragma unroll
    for (int i = 0; i < 4; i++)
#pragma unroll
      for (int j = 0; j < 4; j++)
        acc[i][j] = __builtin_amdgcn_mfma_f32_16x16x32_bf16(af[i], bfr[j], acc[i][j], 0, 0, 0);
    __syncthreads();
  }

  const int mr4 = (lane >> 4) * 4, nc = lane & 15;
#pragma unroll
  for (int j = 0; j < 4; j++) {
    const int gc = bn * 128 + wn + j * 16 + nc;
    const float bv = bias[gc];
#pragma unroll
    for (int i = 0; i < 4; i++) {
      const int gr0 = bm * 128 + wm + i * 16 + mr4;
#pragma unroll
      for (int r = 0; r < 4; r++) {
        float v = acc[i][j][r] + bv;
        if (OUT_BF16)
          ((unsigned short*)Out)[(size_t)(gr0 + r) * Nout + gc] = f2b(v);
        else
          ((float*)Out)[(size_t)(gr0 + r) * Nout + gc] = v;
      }
    }
  }
}

// ---------------------------------------------------------------------------
// pass_a (split fp32): one block per (bh, split); split handles TILES_PER_BLK
// tiles of 128 tokens. Threads t<128 compute phi_k (fp32, full 64-dim softmax
// in regs) + stage v (bf16 raw). All 4 waves accumulate: wave w handles
// tokens [w*32,w*32+32) of the tile; lane owns d-block dg*4 x e-block eg*16.
// Cross-wave merge via LDS (reusing sphi, stride-33 padded), then plain
// (non-atomic) float4 stores to a per-(bh,split) partial slice of kvP.
// reduce_kv folds the SPLIT_A partials into kvG.
// ---------------------------------------------------------------------------
__global__ __launch_bounds__(256) void pass_a(
    const unsigned short* __restrict__ qkv, const float* __restrict__ rope,
    float* __restrict__ kvP) {
  __shared__ float sphi[128 * 65];               // 33,280 B (pad 65: no conflicts)
  __shared__ __align__(16) unsigned short sv[128 * 64];  // 16,384 B
  const int bh = blockIdx.x, b = bh / 12, h = bh % 12;
  const int sp = blockIdx.y;
  const int t = threadIdx.x;
  const int lane = t & 63, wave = t >> 6;
  const int dg = lane >> 2;   // d = dg*4 + i
  const int eg = lane & 3;    // e = eg*16 + j
  float acc[4][16] = {};
  float ks4[4] = {};

  const int tile0 = sp * TILES_PER_BLK;
  for (int tile = tile0; tile < tile0 + TILES_PER_BLK; tile++) {
    __syncthreads();
    if (t < 128) {
      const int n = tile * 128 + t;
      const size_t rowb = (size_t)(b * 4096 + n) * 2304;
      const unsigned short* kp = qkv + rowb + 768 + h * 64;
      float kk[64];
#pragma unroll
      for (int c = 0; c < 8; c++) {
        uint4 u = *(const uint4*)(kp + c * 8);
        unpack2(u.x, kk[c * 8 + 0], kk[c * 8 + 1]);
        unpack2(u.y, kk[c * 8 + 2], kk[c * 8 + 3]);
        unpack2(u.z, kk[c * 8 + 4], kk[c * 8 + 5]);
        unpack2(u.w, kk[c * 8 + 6], kk[c * 8 + 7]);
      }
      if (n > 0) {
        const float* rp = rope + (size_t)(n - 1) * 128;
#pragma unroll
        for (int c = 0; c < 8; c++) {
          float sn[8], cs[8];
          *(float4*)&sn[0] = *(const float4*)(rp + c * 8);
          *(float4*)&sn[4] = *(const float4*)(rp + c * 8 + 4);
          *(float4*)&cs[0] = *(const float4*)(rp + 64 + c * 8);
          *(float4*)&cs[4] = *(const float4*)(rp + 64 + c * 8 + 4);
#pragma unroll
          for (int i = 0; i < 4; i++) {
            float e = kk[c * 8 + 2 * i], o = kk[c * 8 + 2 * i + 1];
            kk[c * 8 + 2 * i] = e * cs[2 * i] - o * sn[2 * i];
            kk[c * 8 + 2 * i + 1] = o * cs[2 * i + 1] + e * sn[2 * i + 1];
          }
        }
      }
      float mx = kk[0];
#pragma unroll
      for (int i = 1; i < 64; i++) mx = fmaxf(mx, kk[i]);
      float s = 0.f;
#pragma unroll
      for (int i = 0; i < 64; i++) { float e = __expf(kk[i] - mx); kk[i] = e; s += e; }
      const float inv = 1.f / s;
#pragma unroll
      for (int d = 0; d < 64; d++) sphi[t * 65 + d] = kk[d] * inv;
      const unsigned short* vp = qkv + rowb + 1536 + h * 64;
#pragma unroll
      for (int c = 0; c < 8; c++)
        *(uint4*)&sv[t * 64 + c * 8] = *(const uint4*)(vp + c * 8);
    }
    __syncthreads();
    const int n0 = wave * 32;
    for (int nn = n0; nn < n0 + 32; nn++) {
      float p[4];
#pragma unroll
      for (int i = 0; i < 4; i++) p[i] = sphi[nn * 65 + dg * 4 + i];
#pragma unroll
      for (int i = 0; i < 4; i++) ks4[i] += p[i];
      float vv[16];
      {
        uint4 u0 = *(const uint4*)&sv[nn * 64 + eg * 16];
        uint4 u1 = *(const uint4*)&sv[nn * 64 + eg * 16 + 8];
        unpack2(u0.x, vv[0], vv[1]);   unpack2(u0.y, vv[2], vv[3]);
        unpack2(u0.z, vv[4], vv[5]);   unpack2(u0.w, vv[6], vv[7]);
        unpack2(u1.x, vv[8], vv[9]);   unpack2(u1.y, vv[10], vv[11]);
        unpack2(u1.z, vv[12], vv[13]); unpack2(u1.w, vv[14], vv[15]);
      }
#pragma unroll
      for (int i = 0; i < 4; i++)
#pragma unroll
        for (int j = 0; j < 16; j++)
          acc[i][j] += p[i] * vv[j];
    }
  }

  // ---- cross-wave merge via LDS (reuse sphi as [192][33] f32 scratch) ----
  __syncthreads();
  float* sred = sphi;
  float* o = kvP + ((size_t)bh * SPLIT_A + sp) * 4160;
#pragma unroll
  for (int half = 0; half < 2; half++) {
    if (wave != 0) {
      float* row = &sred[((wave - 1) * 64 + lane) * 33];
#pragma unroll
      for (int i = 0; i < 4; i++)
#pragma unroll
        for (int jj = 0; jj < 8; jj++) row[i * 8 + jj] = acc[i][half * 8 + jj];
    }
    __syncthreads();
    if (wave == 0) {
#pragma unroll
      for (int jj = 0; jj < 8; jj++) {
        float4 s4;
        float sv4[4];
#pragma unroll
        for (int i = 0; i < 4; i++) {
          float s = acc[i][half * 8 + jj];
#pragma unroll
          for (int w = 0; w < 3; w++) s += sred[(w * 64 + lane) * 33 + i * 8 + jj];
          sv4[i] = s;
        }
        s4.x = sv4[0]; s4.y = sv4[1]; s4.z = sv4[2]; s4.w = sv4[3];
        const int e = eg * 16 + half * 8 + jj;
        *(float4*)&o[e * 64 + dg * 4] = s4;
      }
    }
    __syncthreads();
  }
  // ---- ksum merge ----
  if (wave != 0) {
#pragma unroll
    for (int i = 0; i < 4; i++) sred[((wave - 1) * 64 + lane) * 5 + i] = ks4[i];
  }
  __syncthreads();
  if (wave == 0 && eg == 0) {
    float4 s4;
    float sv4[4];
#pragma unroll
    for (int i = 0; i < 4; i++) {
      float s = ks4[i];
#pragma unroll
      for (int w = 0; w < 3; w++) s += sred[(w * 64 + lane) * 5 + i];
      sv4[i] = s;
    }
    s4.x = sv4[0]; s4.y = sv4[1]; s4.z = sv4[2]; s4.w = sv4[3];
    *(float4*)&o[4096 + dg * 4] = s4;
  }
}

// ---------------------------------------------------------------------------
// reduce_kv: kvG[bh][r] = sum_{sp<SPLIT_A} kvP[bh][sp][r]. 96*4160 outputs.
// ---------------------------------------------------------------------------
__global__ __launch_bounds__(256) void reduce_kv(
    const float* __restrict__ kvP, float* __restrict__ kvG) {
  const int i = blockIdx.x * 256 + threadIdx.x;
  if (i >= 96 * 4160) return;
  const int bh = i / 4160, r = i - bh * 4160;
  const float* p = kvP + (size_t)bh * SPLIT_A * 4160 + r;
  float s = 0.f;
#pragma unroll
  for (int sp = 0; sp < SPLIT_A; sp++) s += p[(size_t)sp * 4160];
  kvG[i] = s;
}

// ---------------------------------------------------------------------------
// pass_b (simple): one thread per token. phi_q fp32 in regs; kv staged to
// LDS as bf16 [e][d]; out[n,e] = (sum_d phi_q[d]*kv[d,e]) / (z+eps), bf16.
// All lanes read the same LDS address (broadcast, conflict-free).
// ---------------------------------------------------------------------------
__global__ __launch_bounds__(256) void pass_b(
    const unsigned short* __restrict__ qkv, const float* __restrict__ rope,
    const float* __restrict__ kvG, unsigned short* __restrict__ attn) {
  __shared__ __align__(16) unsigned short skvh[4096];  // [e][d] bf16
  __shared__ float sks[64];
  const int bh = blockIdx.x, b = bh / 12, h = bh % 12;
  const int t = threadIdx.x;
  const float* kvb = kvG + (size_t)bh * 4160;
  {
    const float* src = kvb + t * 16;
    unsigned short tmp[16];
#pragma unroll
    for (int i = 0; i < 16; i++) tmp[i] = f2b(src[i]);
    *(uint4*)&skvh[t * 16] = *(uint4*)&tmp[0];
    *(uint4*)&skvh[t * 16 + 8] = *(uint4*)&tmp[8];
  }
  if (t < 64) sks[t] = kvb[4096 + t];
  __syncthreads();

  const int n = blockIdx.y * 256 + t;
  const size_t rowb = (size_t)(b * 4096 + n) * 2304;
  const unsigned short* qp = qkv + rowb + h * 64;
  float ph[64];
#pragma unroll
  for (int c = 0; c < 8; c++) {
    uint4 u = *(const uint4*)(qp + c * 8);
    unpack2(u.x, ph[c * 8 + 0], ph[c * 8 + 1]);
    unpack2(u.y, ph[c * 8 + 2], ph[c * 8 + 3]);
    unpack2(u.z, ph[c * 8 + 4], ph[c * 8 + 5]);
    unpack2(u.w, ph[c * 8 + 6], ph[c * 8 + 7]);
  }
  if (n > 0) {
    const float* rp = rope + (size_t)(n - 1) * 128;
#pragma unroll
    for (int c = 0; c < 8; c++) {
      float sn[8], cs[8];
      *(float4*)&sn[0] = *(const float4*)(rp + c * 8);
      *(float4*)&sn[4] = *(const float4*)(rp + c * 8 + 4);
      *(float4*)&cs[0] = *(const float4*)(rp + 64 + c * 8);
      *(float4*)&cs[4] = *(const float4*)(rp + 64 + c * 8 + 4);
#pragma unroll
      for (int i = 0; i < 4; i++) {
        float e = ph[c * 8 + 2 * i], o = ph[c * 8 + 2 * i + 1];
        ph[c * 8 + 2 * i] = e * cs[2 * i] - o * sn[2 * i];
        ph[c * 8 + 2 * i + 1] = o * cs[2 * i + 1] + e * sn[2 * i + 1];
      }
    }
  }
  float mx = ph[0];
#pragma unroll
  for (int i = 1; i < 64; i++) mx = fmaxf(mx, ph[i]);
  float s = 0.f;
#pragma unroll
  for (int i = 0; i < 64; i++) { float e = __expf(ph[i] - mx); ph[i] = e; s += e; }
  const float inv = 1.f / s;
  float z = 0.f;
#pragma unroll
  for (int i = 0; i < 64; i++) { ph[i] *= inv; z += ph[i] * sks[i]; }
  const float zi = 1.f / (z + 1e-5f);

  unsigned short* orow = attn + (size_t)(b * 4096 + n) * 768 + h * 64;
  unsigned short tmp8[8];
  for (int e = 0; e < 64; e++) {
    float acc = 0.f;
#pragma unroll
    for (int c = 0; c < 8; c++) {
      uint4 u = *(const uint4*)&skvh[e * 64 + c * 8];
      float f0, f1;
      unpack2(u.x, f0, f1); acc += ph[c * 8 + 0] * f0 + ph[c * 8 + 1] * f1;
      unpack2(u.y, f0, f1); acc += ph[c * 8 + 2] * f0 + ph[c * 8 + 3] * f1;
      unpack2(u.z, f0, f1); acc += ph[c * 8 + 4] * f0 + ph[c * 8 + 5] * f1;
      unpack2(u.w, f0, f1); acc += ph[c * 8 + 6] * f0 + ph[c * 8 + 7] * f1;
    }
    tmp8[e & 7] = f2b(acc * zi);
    if ((e & 7) == 7) *(uint4*)&orow[e - 7] = *(uint4*)&tmp8[0];
  }
}

// ---------------------------------------------------------------------------
// LayerNorm over C=768, in-place on bf16 buffer; gamma/beta fp32.
// ---------------------------------------------------------------------------
__global__ __launch_bounds__(256) void ln_kernel(
    unsigned short* __restrict__ buf, const float* __restrict__ g,
    const float* __restrict__ be) {
  const int row = blockIdx.x;
  const int t = threadIdx.x;
  unsigned short* p = buf + (size_t)row * 768;
  const float x0 = b2f(p[t]), x1 = b2f(p[t + 256]), x2 = b2f(p[t + 512]);
  float s = x0 + x1 + x2;
  float ss = x0 * x0 + x1 * x1 + x2 * x2;
#pragma unroll
  for (int m = 1; m < 64; m <<= 1) { s += __shfl_xor(s, m); ss += __shfl_xor(ss, m); }
  __shared__ float red[8];
  const int wave = t >> 6, lane = t & 63;
  if (lane == 0) { red[wave] = s; red[4 + wave] = ss; }
  __syncthreads();
  s = red[0] + red[1] + red[2] + red[3];
  ss = red[4] + red[5] + red[6] + red[7];
  const float mean = s * (1.f / 768.f);
  const float var = ss * (1.f / 768.f) - mean * mean;
  const float rsq = rsqrtf(var + 1e-5f);
  p[t] = f2b((x0 - mean) * rsq * g[t] + be[t]);
  p[t + 256] = f2b((x1 - mean) * rsq * g[t + 256] + be[t + 256]);
  p[t + 512] = f2b((x2 - mean) * rsq * g[t + 512] + be[t + 512]);
}

__global__ void setup_bias(const float* qb, const float* vb, const float* pb,
                           float* qkvb, float* projb) {
  const int i = blockIdx.x * 256 + threadIdx.x;
  if (i < 2304) qkvb[i] = (i < 768) ? qb[i] : (i >= 1536 ? vb[i - 1536] : 0.f);
  if (i < 768) projb[i] = pb[i];
}

// ---------------------------------------------------------------------------
extern "C" void kernel_launch(void* const* d_in, const int* in_sizes, int n_in,
                              void* d_out, int out_size, void* d_ws, size_t ws_size,
                              hipStream_t stream) {
  (void)in_sizes; (void)n_in; (void)out_size; (void)ws_size;
  const float* x      = (const float*)d_in[0];
  const float* rope   = (const float*)d_in[1];
  const float* qkv_w  = (const float*)d_in[2];
  const float* q_bias = (const float*)d_in[3];
  const float* v_bias = (const float*)d_in[4];
  const float* norm_g = (const float*)d_in[5];
  const float* norm_b = (const float*)d_in[6];
  const float* proj_w = (const float*)d_in[7];
  const float* proj_b = (const float*)d_in[8];

  char* ws = (char*)d_ws;
  unsigned short* qkv  = (unsigned short*)ws;                // 150,994,944 B
  unsigned short* attn = (unsigned short*)(ws + 150994944);  //  50,331,648 B
  unsigned short* xbf  = attn;  // aliased: x_bf16 dead before attn is written
  float* kvP   = (float*)(ws + 150994944);  // aliased: partials dead before attn
  float* kvG   = (float*)(ws + 201326592);                   //   1,597,440 B
  float* qkvb  = (float*)(ws + 202924032);
  float* projb = (float*)(ws + 202933248);
  unsigned short* wbf  = (unsigned short*)(ws + 202936320);  //   3,538,944 B
  unsigned short* pwbf = (unsigned short*)(ws + 206475264);  //   1,179,648 B

  f32_to_bf16<<<dim3(12288), dim3(256), 0, stream>>>(x, xbf, 25165824);
  f32_to_bf16<<<dim3(864), dim3(256), 0, stream>>>(qkv_w, wbf, 1769472);
  f32_to_bf16<<<dim3(288), dim3(256), 0, stream>>>(proj_w, pwbf, 589824);
  setup_bias<<<dim3(9), dim3(256), 0, stream>>>(q_bias, v_bias, proj_b, qkvb, projb);
  // qkv = x @ qkv_w^T + qkv_bias (M=32768, K=768, Nout=2304), bf16 out
  // grid 4608 = 18 bn x 256 bm, XCD-swizzled (4608 % 8 == 0)
  gemm_bt<1><<<dim3(4608), dim3(256), 0, stream>>>(xbf, wbf, qkvb, qkv, 32768, 768, 2304, 18);
  // NOTE: xbf (== kvP region) is dead from here on.
  // kv / ksum partial reduction, 16-way token split (fp32, contention-free)
  pass_a<<<dim3(96, SPLIT_A), dim3(256), 0, stream>>>(qkv, rope, kvP);
  // fold partials into kvG
  reduce_kv<<<dim3(1560), dim3(256), 0, stream>>>(kvP, kvG);
  // attn = phi_q @ kv / (z + eps) (simple fp32 -> bf16); overwrites kvP region
  pass_b<<<dim3(96, 16), dim3(256), 0, stream>>>(qkv, rope, kvG, attn);
  // LayerNorm in-place
  ln_kernel<<<dim3(32768), dim3(256), 0, stream>>>(attn, norm_g, norm_b);
  // out = ln @ proj_w^T + proj_b (M=32768, K=768, Nout=768) -> d_out fp32
  // grid 1536 = 6 bn x 256 bm, XCD-swizzled (1536 % 8 == 0)
  gemm_bt<0><<<dim3(1536), dim3(256), 0, stream>>>(attn, pwbf, projb, d_out, 32768, 768, 768, 6);
}

// Round 4
// 653.066 us; speedup vs baseline: 1.3406x; 1.0075x over previous
//
#include <hip/hip_runtime.h>
#include <stdint.h>

// ---------------------------------------------------------------------------
// EvaLinearAttention on MI355X (gfx950).
// B=8, N=4096, C=768, H=12, D=64, npt=1. I/O fp32; GEMMs bf16 MFMA;
// attention middle: fp32 vector implementation.
// R1: pass_a 16-way token split (310us -> off top-5). Total 875 -> 666us.
// R2: XCD-chunked swizzle on GEMMs: FETCH 250->124MB, dur 190->180us.
//     GEMM now structure-bound (MfmaUtil 29%), not HBM-bound.
// R3: (a) BK=64 (half the barriers/K-steps, 32KiB LDS) with XOR-swizzled
//     source+read (linear [128][64] would be 16-way bank conflict);
//     (b) transposed-MFMA epilogue -> packed 8B/16B C-stores (was 64x2B);
//     (c) pass_b kv staged as f32 (no per-element unpack in inner loop);
//     (d) merged prep kernel (w/pw convert + bias).
// ---------------------------------------------------------------------------

typedef __attribute__((ext_vector_type(8))) short short8;
typedef __attribute__((ext_vector_type(4))) float floatx4;

#define SPLIT_A 16
#define TILES_PER_BLK (32 / SPLIT_A)

__device__ __forceinline__ float b2f(unsigned short u) {
  union { unsigned int i; float f; } v; v.i = ((unsigned int)u) << 16; return v.f;
}
__device__ __forceinline__ unsigned short f2b(float f) {
  union { float f; unsigned int i; } v; v.f = f;
  unsigned int i = v.i;
  unsigned int r = (i + 0x7FFFu + ((i >> 16) & 1u)) >> 16;  // RNE
  return (unsigned short)r;
}
__device__ __forceinline__ void unpack2(unsigned int u, float& a, float& b) {
  union { unsigned int i; float f; } x, y;
  x.i = u << 16; y.i = u & 0xFFFF0000u;
  a = x.f; b = y.f;
}

__device__ __forceinline__ void stage16(const void* g, void* l) {
#if defined(__has_builtin) && __has_builtin(__builtin_amdgcn_global_load_lds)
  __builtin_amdgcn_global_load_lds(
      (const __attribute__((address_space(1))) unsigned int*)g,
      (__attribute__((address_space(3))) unsigned int*)l, 16, 0, 0);
#else
  *(uint4*)l = *(const uint4*)g;
#endif
}

// ---------------------------------------------------------------------------
__global__ __launch_bounds__(256) void f32_to_bf16(
    const float* __restrict__ in, unsigned short* __restrict__ out, int n) {
  const int i = (blockIdx.x * 256 + threadIdx.x) * 8;
  if (i + 7 < n) {
    float4 a = *(const float4*)(in + i);
    float4 b = *(const float4*)(in + i + 4);
    unsigned short tmp[8] = {f2b(a.x), f2b(a.y), f2b(a.z), f2b(a.w),
                             f2b(b.x), f2b(b.y), f2b(b.z), f2b(b.w)};
    *(uint4*)(out + i) = *(uint4*)tmp;
  }
}

// ---------------------------------------------------------------------------
// prep: convert qkv_w and proj_w to bf16, build fused qkv bias + proj bias.
// blocks [0,864): w; [864,1152): pw; [1152,1161): bias.
// ---------------------------------------------------------------------------
__global__ __launch_bounds__(256) void prep(
    const float* __restrict__ w, const float* __restrict__ pw,
    const float* __restrict__ qb, const float* __restrict__ vb,
    const float* __restrict__ pb,
    unsigned short* __restrict__ wbf, unsigned short* __restrict__ pwbf,
    float* __restrict__ qkvb, float* __restrict__ projb) {
  const int blk = blockIdx.x, t = threadIdx.x;
  if (blk < 1152) {
    const float* src = (blk < 864) ? w : pw;
    unsigned short* dst = (blk < 864) ? wbf : pwbf;
    const int i = ((blk < 864 ? blk : blk - 864) * 256 + t) * 8;
    float4 a = *(const float4*)(src + i);
    float4 b = *(const float4*)(src + i + 4);
    unsigned short tmp[8] = {f2b(a.x), f2b(a.y), f2b(a.z), f2b(a.w),
                             f2b(b.x), f2b(b.y), f2b(b.z), f2b(b.w)};
    *(uint4*)(dst + i) = *(uint4*)tmp;
  } else {
    const int i = (blk - 1152) * 256 + t;
    if (i < 2304) qkvb[i] = (i < 768) ? qb[i] : (i >= 1536 ? vb[i - 1536] : 0.f);
    if (i < 768) projb[i] = pb[i];
  }
}

// ---------------------------------------------------------------------------
// bf16 GEMM, B^T: Out[M,Nout] = A[M,K] * W[Nout,K]^T + bias.
// 128x128 tile, BK=64, XCD-chunked swizzle (gridDim.x % 8 == 0).
// LDS layout: [128][64] bf16 with XOR slot-swizzle (slot ^= row&7, 16B slots)
// applied on the global SOURCE (dest stays linear for global_load_lds) and
// on the ds_read address -- rule-21 both-sides involution. Post-swizzle
// fragment reads are 2-way (free) instead of 16-way.
// Epilogue: mfma(bfr, af) computes the transposed fragment so each lane owns
// 4 consecutive output columns -> packed 8B (bf16) / 16B (fp32) stores.
// ---------------------------------------------------------------------------
template <int OUT_BF16>
__global__ __launch_bounds__(256) void gemm_bt(
    const unsigned short* __restrict__ A, const unsigned short* __restrict__ W,
    const float* __restrict__ bias, void* __restrict__ Out,
    int M, int K, int Nout, int nbn) {
  __shared__ __align__(16) unsigned short sA[128 * 64];
  __shared__ __align__(16) unsigned short sB[128 * 64];
  const int nwg = gridDim.x;
  const int orig = blockIdx.x;
  const int wg = (orig & 7) * (nwg >> 3) + (orig >> 3);  // bijective: nwg%8==0
  const int bm = wg / nbn;
  const int bn = wg - bm * nbn;
  const int t = threadIdx.x;
  const int lane = t & 63, wave = t >> 6;
  const int wm = (wave >> 1) * 64, wn = (wave & 1) * 64;
  // staging: 4 chunks of 32 rows; thread t covers row (t>>3), swizzled slot.
  const int lr = t >> 3;                            // 0..31
  const int xc = ((t & 7) ^ (lr & 7)) * 8;          // source col, pre-swizzled
  const size_t baseA = (size_t)(bm * 128 + lr) * K + xc;
  const size_t baseB = (size_t)(bn * 128 + lr) * K + xc;
  floatx4 acc[4][4] = {};

  const int mr = lane & 15, kq8 = (lane >> 4);      // fragment row / k-slot
  for (int k0 = 0; k0 < K; k0 += 64) {
#pragma unroll
    for (int c = 0; c < 4; c++) {
      stage16(A + baseA + (size_t)(c * 32) * K + k0, &sA[c * 2048 + t * 8]);
      stage16(W + baseB + (size_t)(c * 32) * K + k0, &sB[c * 2048 + t * 8]);
    }
    __syncthreads();
#pragma unroll
    for (int kk = 0; kk < 2; kk++) {
      short8 af[4], bfr[4];
#pragma unroll
      for (int i = 0; i < 4; i++) {
        const int row = wm + i * 16 + mr;
        af[i] = *(const short8*)&sA[row * 64 + ((kk * 4 + kq8) ^ (row & 7)) * 8];
      }
#pragma unroll
      for (int j = 0; j < 4; j++) {
        const int row = wn + j * 16 + mr;
        bfr[j] = *(const short8*)&sB[row * 64 + ((kk * 4 + kq8) ^ (row & 7)) * 8];
      }
#pragma unroll
      for (int i = 0; i < 4; i++)
#pragma unroll
        for (int j = 0; j < 4; j++)
          acc[i][j] = __builtin_amdgcn_mfma_f32_16x16x32_bf16(bfr[j], af[i], acc[i][j], 0, 0, 0);
    }
    __syncthreads();
  }

  // Transposed fragment: mfma-row = (lane>>4)*4+r = W-row = out COL,
  // mfma-col = lane&15 = A-row = out ROW.
  const int ur = (lane >> 4) * 4;   // out-col offset within 16-block
  const int vr = lane & 15;         // out-row within 16-block
#pragma unroll
  for (int i = 0; i < 4; i++) {
    const int gr = bm * 128 + wm + i * 16 + vr;
#pragma unroll
    for (int j = 0; j < 4; j++) {
      const int gc0 = bn * 128 + wn + j * 16 + ur;
      const float4 bv = *(const float4*)&bias[gc0];
      const float v0 = acc[i][j][0] + bv.x, v1 = acc[i][j][1] + bv.y;
      const float v2 = acc[i][j][2] + bv.z, v3 = acc[i][j][3] + bv.w;
      if (OUT_BF16) {
        unsigned short p[4] = {f2b(v0), f2b(v1), f2b(v2), f2b(v3)};
        *(uint2*)((unsigned short*)Out + (size_t)gr * Nout + gc0) = *(const uint2*)p;
      } else {
        float4 o4; o4.x = v0; o4.y = v1; o4.z = v2; o4.w = v3;
        *(float4*)((float*)Out + (size_t)gr * Nout + gc0) = o4;
      }
    }
  }
}

// ---------------------------------------------------------------------------
// pass_a (split fp32): one block per (bh, split); split handles TILES_PER_BLK
// tiles of 128 tokens. Threads t<128 compute phi_k (fp32, full 64-dim softmax
// in regs) + stage v (bf16 raw). All 4 waves accumulate: wave w handles
// tokens [w*32,w*32+32) of the tile; lane owns d-block dg*4 x e-block eg*16.
// Cross-wave merge via LDS, then plain float4 stores to per-(bh,split) kvP.
// ---------------------------------------------------------------------------
__global__ __launch_bounds__(256) void pass_a(
    const unsigned short* __restrict__ qkv, const float* __restrict__ rope,
    float* __restrict__ kvP) {
  __shared__ float sphi[128 * 65];               // 33,280 B (pad 65: no conflicts)
  __shared__ __align__(16) unsigned short sv[128 * 64];  // 16,384 B
  const int bh = blockIdx.x, b = bh / 12, h = bh % 12;
  const int sp = blockIdx.y;
  const int t = threadIdx.x;
  const int lane = t & 63, wave = t >> 6;
  const int dg = lane >> 2;   // d = dg*4 + i
  const int eg = lane & 3;    // e = eg*16 + j
  float acc[4][16] = {};
  float ks4[4] = {};

  const int tile0 = sp * TILES_PER_BLK;
  for (int tile = tile0; tile < tile0 + TILES_PER_BLK; tile++) {
    __syncthreads();
    if (t < 128) {
      const int n = tile * 128 + t;
      const size_t rowb = (size_t)(b * 4096 + n) * 2304;
      const unsigned short* kp = qkv + rowb + 768 + h * 64;
      float kk[64];
#pragma unroll
      for (int c = 0; c < 8; c++) {
        uint4 u = *(const uint4*)(kp + c * 8);
        unpack2(u.x, kk[c * 8 + 0], kk[c * 8 + 1]);
        unpack2(u.y, kk[c * 8 + 2], kk[c * 8 + 3]);
        unpack2(u.z, kk[c * 8 + 4], kk[c * 8 + 5]);
        unpack2(u.w, kk[c * 8 + 6], kk[c * 8 + 7]);
      }
      if (n > 0) {
        const float* rp = rope + (size_t)(n - 1) * 128;
#pragma unroll
        for (int c = 0; c < 8; c++) {
          float sn[8], cs[8];
          *(float4*)&sn[0] = *(const float4*)(rp + c * 8);
          *(float4*)&sn[4] = *(const float4*)(rp + c * 8 + 4);
          *(float4*)&cs[0] = *(const float4*)(rp + 64 + c * 8);
          *(float4*)&cs[4] = *(const float4*)(rp + 64 + c * 8 + 4);
#pragma unroll
          for (int i = 0; i < 4; i++) {
            float e = kk[c * 8 + 2 * i], o = kk[c * 8 + 2 * i + 1];
            kk[c * 8 + 2 * i] = e * cs[2 * i] - o * sn[2 * i];
            kk[c * 8 + 2 * i + 1] = o * cs[2 * i + 1] + e * sn[2 * i + 1];
          }
        }
      }
      float mx = kk[0];
#pragma unroll
      for (int i = 1; i < 64; i++) mx = fmaxf(mx, kk[i]);
      float s = 0.f;
#pragma unroll
      for (int i = 0; i < 64; i++) { float e = __expf(kk[i] - mx); kk[i] = e; s += e; }
      const float inv = 1.f / s;
#pragma unroll
      for (int d = 0; d < 64; d++) sphi[t * 65 + d] = kk[d] * inv;
      const unsigned short* vp = qkv + rowb + 1536 + h * 64;
#pragma unroll
      for (int c = 0; c < 8; c++)
        *(uint4*)&sv[t * 64 + c * 8] = *(const uint4*)(vp + c * 8);
    }
    __syncthreads();
    const int n0 = wave * 32;
    for (int nn = n0; nn < n0 + 32; nn++) {
      float p[4];
#pragma unroll
      for (int i = 0; i < 4; i++) p[i] = sphi[nn * 65 + dg * 4 + i];
#pragma unroll
      for (int i = 0; i < 4; i++) ks4[i] += p[i];
      float vv[16];
      {
        uint4 u0 = *(const uint4*)&sv[nn * 64 + eg * 16];
        uint4 u1 = *(const uint4*)&sv[nn * 64 + eg * 16 + 8];
        unpack2(u0.x, vv[0], vv[1]);   unpack2(u0.y, vv[2], vv[3]);
        unpack2(u0.z, vv[4], vv[5]);   unpack2(u0.w, vv[6], vv[7]);
        unpack2(u1.x, vv[8], vv[9]);   unpack2(u1.y, vv[10], vv[11]);
        unpack2(u1.z, vv[12], vv[13]); unpack2(u1.w, vv[14], vv[15]);
      }
#pragma unroll
      for (int i = 0; i < 4; i++)
#pragma unroll
        for (int j = 0; j < 16; j++)
          acc[i][j] += p[i] * vv[j];
    }
  }

  // ---- cross-wave merge via LDS (reuse sphi as scratch) ----
  __syncthreads();
  float* sred = sphi;
  float* o = kvP + ((size_t)bh * SPLIT_A + sp) * 4160;
#pragma unroll
  for (int half = 0; half < 2; half++) {
    if (wave != 0) {
      float* row = &sred[((wave - 1) * 64 + lane) * 33];
#pragma unroll
      for (int i = 0; i < 4; i++)
#pragma unroll
        for (int jj = 0; jj < 8; jj++) row[i * 8 + jj] = acc[i][half * 8 + jj];
    }
    __syncthreads();
    if (wave == 0) {
#pragma unroll
      for (int jj = 0; jj < 8; jj++) {
        float4 s4;
        float sv4[4];
#pragma unroll
        for (int i = 0; i < 4; i++) {
          float s = acc[i][half * 8 + jj];
#pragma unroll
          for (int w = 0; w < 3; w++) s += sred[(w * 64 + lane) * 33 + i * 8 + jj];
          sv4[i] = s;
        }
        s4.x = sv4[0]; s4.y = sv4[1]; s4.z = sv4[2]; s4.w = sv4[3];
        const int e = eg * 16 + half * 8 + jj;
        *(float4*)&o[e * 64 + dg * 4] = s4;
      }
    }
    __syncthreads();
  }
  // ---- ksum merge ----
  if (wave != 0) {
#pragma unroll
    for (int i = 0; i < 4; i++) sred[((wave - 1) * 64 + lane) * 5 + i] = ks4[i];
  }
  __syncthreads();
  if (wave == 0 && eg == 0) {
    float4 s4;
    float sv4[4];
#pragma unroll
    for (int i = 0; i < 4; i++) {
      float s = ks4[i];
#pragma unroll
      for (int w = 0; w < 3; w++) s += sred[(w * 64 + lane) * 5 + i];
      sv4[i] = s;
    }
    s4.x = sv4[0]; s4.y = sv4[1]; s4.z = sv4[2]; s4.w = sv4[3];
    *(float4*)&o[4096 + dg * 4] = s4;
  }
}

// ---------------------------------------------------------------------------
// reduce_kv: kvG[bh][r] = sum_{sp<SPLIT_A} kvP[bh][sp][r]. 96*4160 outputs.
// ---------------------------------------------------------------------------
__global__ __launch_bounds__(256) void reduce_kv(
    const float* __restrict__ kvP, float* __restrict__ kvG) {
  const int i = blockIdx.x * 256 + threadIdx.x;
  if (i >= 96 * 4160) return;
  const int bh = i / 4160, r = i - bh * 4160;
  const float* p = kvP + (size_t)bh * SPLIT_A * 4160 + r;
  float s = 0.f;
#pragma unroll
  for (int sp = 0; sp < SPLIT_A; sp++) s += p[(size_t)sp * 4160];
  kvG[i] = s;
}

// ---------------------------------------------------------------------------
// pass_b: one thread per token. phi_q fp32 in regs; kv staged to LDS as f32
// [e][d] (16KB, broadcast reads -> conflict-free); out bf16.
// ---------------------------------------------------------------------------
__global__ __launch_bounds__(256) void pass_b(
    const unsigned short* __restrict__ qkv, const float* __restrict__ rope,
    const float* __restrict__ kvG, unsigned short* __restrict__ attn) {
  __shared__ __align__(16) float skv[4096];  // [e][d] f32
  __shared__ float sks[64];
  const int bh = blockIdx.x, b = bh / 12, h = bh % 12;
  const int t = threadIdx.x;
  const float* kvb = kvG + (size_t)bh * 4160;
#pragma unroll
  for (int i = 0; i < 4; i++)
    *(float4*)&skv[t * 16 + i * 4] = *(const float4*)&kvb[t * 16 + i * 4];
  if (t < 64) sks[t] = kvb[4096 + t];
  __syncthreads();

  const int n = blockIdx.y * 256 + t;
  const size_t rowb = (size_t)(b * 4096 + n) * 2304;
  const unsigned short* qp = qkv + rowb + h * 64;
  float ph[64];
#pragma unroll
  for (int c = 0; c < 8; c++) {
    uint4 u = *(const uint4*)(qp + c * 8);
    unpack2(u.x, ph[c * 8 + 0], ph[c * 8 + 1]);
    unpack2(u.y, ph[c * 8 + 2], ph[c * 8 + 3]);
    unpack2(u.z, ph[c * 8 + 4], ph[c * 8 + 5]);
    unpack2(u.w, ph[c * 8 + 6], ph[c * 8 + 7]);
  }
  if (n > 0) {
    const float* rp = rope + (size_t)(n - 1) * 128;
#pragma unroll
    for (int c = 0; c < 8; c++) {
      float sn[8], cs[8];
      *(float4*)&sn[0] = *(const float4*)(rp + c * 8);
      *(float4*)&sn[4] = *(const float4*)(rp + c * 8 + 4);
      *(float4*)&cs[0] = *(const float4*)(rp + 64 + c * 8);
      *(float4*)&cs[4] = *(const float4*)(rp + 64 + c * 8 + 4);
#pragma unroll
      for (int i = 0; i < 4; i++) {
        float e = ph[c * 8 + 2 * i], o = ph[c * 8 + 2 * i + 1];
        ph[c * 8 + 2 * i] = e * cs[2 * i] - o * sn[2 * i];
        ph[c * 8 + 2 * i + 1] = o * cs[2 * i + 1] + e * sn[2 * i + 1];
      }
    }
  }
  float mx = ph[0];
#pragma unroll
  for (int i = 1; i < 64; i++) mx = fmaxf(mx, ph[i]);
  float s = 0.f;
#pragma unroll
  for (int i = 0; i < 64; i++) { float e = __expf(ph[i] - mx); ph[i] = e; s += e; }
  const float inv = 1.f / s;
  float z = 0.f;
#pragma unroll
  for (int i = 0; i < 64; i++) { ph[i] *= inv; z += ph[i] * sks[i]; }
  const float zi = 1.f / (z + 1e-5f);

  unsigned short* orow = attn + (size_t)(b * 4096 + n) * 768 + h * 64;
  unsigned short tmp8[8];
  for (int e = 0; e < 64; e++) {
    float a0 = 0.f, a1 = 0.f, a2 = 0.f, a3 = 0.f;
#pragma unroll
    for (int c = 0; c < 16; c++) {
      float4 f = *(const float4*)&skv[e * 64 + c * 4];
      a0 += ph[c * 4 + 0] * f.x; a1 += ph[c * 4 + 1] * f.y;
      a2 += ph[c * 4 + 2] * f.z; a3 += ph[c * 4 + 3] * f.w;
    }
    tmp8[e & 7] = f2b(((a0 + a1) + (a2 + a3)) * zi);
    if ((e & 7) == 7) *(uint4*)&orow[e - 7] = *(uint4*)&tmp8[0];
  }
}

// ---------------------------------------------------------------------------
// LayerNorm over C=768, in-place on bf16 buffer; gamma/beta fp32.
// ---------------------------------------------------------------------------
__global__ __launch_bounds__(256) void ln_kernel(
    unsigned short* __restrict__ buf, const float* __restrict__ g,
    const float* __restrict__ be) {
  const int row = blockIdx.x;
  const int t = threadIdx.x;
  unsigned short* p = buf + (size_t)row * 768;
  const float x0 = b2f(p[t]), x1 = b2f(p[t + 256]), x2 = b2f(p[t + 512]);
  float s = x0 + x1 + x2;
  float ss = x0 * x0 + x1 * x1 + x2 * x2;
#pragma unroll
  for (int m = 1; m < 64; m <<= 1) { s += __shfl_xor(s, m); ss += __shfl_xor(ss, m); }
  __shared__ float red[8];
  const int wave = t >> 6, lane = t & 63;
  if (lane == 0) { red[wave] = s; red[4 + wave] = ss; }
  __syncthreads();
  s = red[0] + red[1] + red[2] + red[3];
  ss = red[4] + red[5] + red[6] + red[7];
  const float mean = s * (1.f / 768.f);
  const float var = ss * (1.f / 768.f) - mean * mean;
  const float rsq = rsqrtf(var + 1e-5f);
  p[t] = f2b((x0 - mean) * rsq * g[t] + be[t]);
  p[t + 256] = f2b((x1 - mean) * rsq * g[t + 256] + be[t + 256]);
  p[t + 512] = f2b((x2 - mean) * rsq * g[t + 512] + be[t + 512]);
}

// ---------------------------------------------------------------------------
extern "C" void kernel_launch(void* const* d_in, const int* in_sizes, int n_in,
                              void* d_out, int out_size, void* d_ws, size_t ws_size,
                              hipStream_t stream) {
  (void)in_sizes; (void)n_in; (void)out_size; (void)ws_size;
  const float* x      = (const float*)d_in[0];
  const float* rope   = (const float*)d_in[1];
  const float* qkv_w  = (const float*)d_in[2];
  const float* q_bias = (const float*)d_in[3];
  const float* v_bias = (const float*)d_in[4];
  const float* norm_g = (const float*)d_in[5];
  const float* norm_b = (const float*)d_in[6];
  const float* proj_w = (const float*)d_in[7];
  const float* proj_b = (const float*)d_in[8];

  char* ws = (char*)d_ws;
  unsigned short* qkv  = (unsigned short*)ws;                // 150,994,944 B
  unsigned short* attn = (unsigned short*)(ws + 150994944);  //  50,331,648 B
  unsigned short* xbf  = attn;  // aliased: x_bf16 dead before attn is written
  float* kvP   = (float*)(ws + 150994944);  // aliased: partials dead before attn
  float* kvG   = (float*)(ws + 201326592);                   //   1,597,440 B
  float* qkvb  = (float*)(ws + 202924032);
  float* projb = (float*)(ws + 202933248);
  unsigned short* wbf  = (unsigned short*)(ws + 202936320);  //   3,538,944 B
  unsigned short* pwbf = (unsigned short*)(ws + 206475264);  //   1,179,648 B

  f32_to_bf16<<<dim3(12288), dim3(256), 0, stream>>>(x, xbf, 25165824);
  prep<<<dim3(1161), dim3(256), 0, stream>>>(qkv_w, proj_w, q_bias, v_bias,
                                             proj_b, wbf, pwbf, qkvb, projb);
  // qkv = x @ qkv_w^T + qkv_bias (M=32768, K=768, Nout=2304), bf16 out
  // grid 4608 = 18 bn x 256 bm, XCD-swizzled (4608 % 8 == 0)
  gemm_bt<1><<<dim3(4608), dim3(256), 0, stream>>>(xbf, wbf, qkvb, qkv, 32768, 768, 2304, 18);
  // NOTE: xbf (== kvP region) is dead from here on.
  // kv / ksum partial reduction, 16-way token split (fp32, contention-free)
  pass_a<<<dim3(96, SPLIT_A), dim3(256), 0, stream>>>(qkv, rope, kvP);
  // fold partials into kvG
  reduce_kv<<<dim3(1560), dim3(256), 0, stream>>>(kvP, kvG);
  // attn = phi_q @ kv / (z + eps) (fp32 -> bf16); overwrites kvP region
  pass_b<<<dim3(96, 16), dim3(256), 0, stream>>>(qkv, rope, kvG, attn);
  // LayerNorm in-place
  ln_kernel<<<dim3(32768), dim3(256), 0, stream>>>(attn, norm_g, norm_b);
  // out = ln @ proj_w^T + proj_b (M=32768, K=768, Nout=768) -> d_out fp32
  // grid 1536 = 6 bn x 256 bm, XCD-swizzled (1536 % 8 == 0)
  gemm_bt<0><<<dim3(1536), dim3(256), 0, stream>>>(attn, pwbf, projb, d_out, 32768, 768, 768, 6);
}

// Round 5
// 648.908 us; speedup vs baseline: 1.3492x; 1.0064x over previous
//
#include <hip/hip_runtime.h>
#include <stdint.h>

// ---------------------------------------------------------------------------
// EvaLinearAttention on MI355X (gfx950).
// B=8, N=4096, C=768, H=12, D=64, npt=1. I/O fp32; GEMMs bf16 MFMA.
// R1: pass_a 16-way token split (310us -> off top-5). 875 -> 666us.
// R2: XCD-chunked swizzle on GEMMs: FETCH 250->124MB, 190->180us.
// R3: BK=64 + LDS swizzle: conflicts 1.4e7->0 but occupancy 32->22%,
//     dur 180->187 (m132 lesson: K-tile vs occupancy net loss at 2-phase).
// R4 (this): revert GEMM to BK=32/16KB (keep transposed packed epilogue +
//     XCD swizzle); MFMA-ize pass_b (was ~1024 LDS broadcast reads/thread;
//     now 16 frag reads + 32 MFMA per wave, phi/kv bf16 in swizzled LDS).
// ---------------------------------------------------------------------------

typedef __attribute__((ext_vector_type(8))) short short8;
typedef __attribute__((ext_vector_type(4))) float floatx4;

#define SPLIT_A 16
#define TILES_PER_BLK (32 / SPLIT_A)

__device__ __forceinline__ float b2f(unsigned short u) {
  union { unsigned int i; float f; } v; v.i = ((unsigned int)u) << 16; return v.f;
}
__device__ __forceinline__ unsigned short f2b(float f) {
  union { float f; unsigned int i; } v; v.f = f;
  unsigned int i = v.i;
  unsigned int r = (i + 0x7FFFu + ((i >> 16) & 1u)) >> 16;  // RNE
  return (unsigned short)r;
}
__device__ __forceinline__ void unpack2(unsigned int u, float& a, float& b) {
  union { unsigned int i; float f; } x, y;
  x.i = u << 16; y.i = u & 0xFFFF0000u;
  a = x.f; b = y.f;
}

__device__ __forceinline__ void stage16(const void* g, void* l) {
#if defined(__has_builtin) && __has_builtin(__builtin_amdgcn_global_load_lds)
  __builtin_amdgcn_global_load_lds(
      (const __attribute__((address_space(1))) unsigned int*)g,
      (__attribute__((address_space(3))) unsigned int*)l, 16, 0, 0);
#else
  *(uint4*)l = *(const uint4*)g;
#endif
}

// ---------------------------------------------------------------------------
__global__ __launch_bounds__(256) void f32_to_bf16(
    const float* __restrict__ in, unsigned short* __restrict__ out, int n) {
  const int i = (blockIdx.x * 256 + threadIdx.x) * 8;
  if (i + 7 < n) {
    float4 a = *(const float4*)(in + i);
    float4 b = *(const float4*)(in + i + 4);
    unsigned short tmp[8] = {f2b(a.x), f2b(a.y), f2b(a.z), f2b(a.w),
                             f2b(b.x), f2b(b.y), f2b(b.z), f2b(b.w)};
    *(uint4*)(out + i) = *(uint4*)tmp;
  }
}

// ---------------------------------------------------------------------------
// prep: convert qkv_w and proj_w to bf16, build fused qkv bias + proj bias.
// ---------------------------------------------------------------------------
__global__ __launch_bounds__(256) void prep(
    const float* __restrict__ w, const float* __restrict__ pw,
    const float* __restrict__ qb, const float* __restrict__ vb,
    const float* __restrict__ pb,
    unsigned short* __restrict__ wbf, unsigned short* __restrict__ pwbf,
    float* __restrict__ qkvb, float* __restrict__ projb) {
  const int blk = blockIdx.x, t = threadIdx.x;
  if (blk < 1152) {
    const float* src = (blk < 864) ? w : pw;
    unsigned short* dst = (blk < 864) ? wbf : pwbf;
    const int i = ((blk < 864 ? blk : blk - 864) * 256 + t) * 8;
    float4 a = *(const float4*)(src + i);
    float4 b = *(const float4*)(src + i + 4);
    unsigned short tmp[8] = {f2b(a.x), f2b(a.y), f2b(a.z), f2b(a.w),
                             f2b(b.x), f2b(b.y), f2b(b.z), f2b(b.w)};
    *(uint4*)(dst + i) = *(uint4*)tmp;
  } else {
    const int i = (blk - 1152) * 256 + t;
    if (i < 2304) qkvb[i] = (i < 768) ? qb[i] : (i >= 1536 ? vb[i - 1536] : 0.f);
    if (i < 768) projb[i] = pb[i];
  }
}

// ---------------------------------------------------------------------------
// bf16 GEMM, B^T: Out[M,Nout] = A[M,K] * W[Nout,K]^T + bias.
// 128x128 tile, BK=32 (16KB LDS, occupancy ~32%), XCD-chunked swizzle.
// mfma(bfr, af) computes the transposed fragment so each lane owns 4
// consecutive output columns -> packed 8B (bf16) / 16B (fp32) stores.
// ---------------------------------------------------------------------------
template <int OUT_BF16>
__global__ __launch_bounds__(256) void gemm_bt(
    const unsigned short* __restrict__ A, const unsigned short* __restrict__ W,
    const float* __restrict__ bias, void* __restrict__ Out,
    int M, int K, int Nout, int nbn) {
  __shared__ __align__(16) unsigned short sA[128 * 32];
  __shared__ __align__(16) unsigned short sB[128 * 32];
  const int nwg = gridDim.x;
  const int orig = blockIdx.x;
  const int wg = (orig & 7) * (nwg >> 3) + (orig >> 3);  // bijective: nwg%8==0
  const int bm = wg / nbn;
  const int bn = wg - bm * nbn;
  const int t = threadIdx.x;
  const int lane = t & 63, wave = t >> 6;
  const int wm = (wave >> 1) * 64, wn = (wave & 1) * 64;
  const int lr = t >> 2;
  const int lc = (t & 3) * 8;
  const size_t baseA = (size_t)(bm * 128 + lr) * K + lc;
  const size_t baseB = (size_t)(bn * 128 + lr) * K + lc;
  floatx4 acc[4][4] = {};

  const int mr = lane & 15, kq = (lane >> 4) * 8;
  for (int k0 = 0; k0 < K; k0 += 32) {
    stage16(A + baseA + k0, &sA[t * 8]);
    stage16(A + baseA + (size_t)64 * K + k0, &sA[2048 + t * 8]);
    stage16(W + baseB + k0, &sB[t * 8]);
    stage16(W + baseB + (size_t)64 * K + k0, &sB[2048 + t * 8]);
    __syncthreads();
    short8 af[4], bfr[4];
#pragma unroll
    for (int i = 0; i < 4; i++) af[i] = *(const short8*)&sA[(wm + i * 16 + mr) * 32 + kq];
#pragma unroll
    for (int j = 0; j < 4; j++) bfr[j] = *(const short8*)&sB[(wn + j * 16 + mr) * 32 + kq];
#pragma unroll
    for (int i = 0; i < 4; i++)
#pragma unroll
      for (int j = 0; j < 4; j++)
        acc[i][j] = __builtin_amdgcn_mfma_f32_16x16x32_bf16(bfr[j], af[i], acc[i][j], 0, 0, 0);
    __syncthreads();
  }

  // Transposed fragment: D-row=(lane>>4)*4+r = W-row = out COL,
  // D-col=lane&15 = A-row = out ROW.
  const int ur = (lane >> 4) * 4;   // out-col quad within 16-block
  const int vr = lane & 15;         // out-row within 16-block
#pragma unroll
  for (int i = 0; i < 4; i++) {
    const int gr = bm * 128 + wm + i * 16 + vr;
#pragma unroll
    for (int j = 0; j < 4; j++) {
      const int gc0 = bn * 128 + wn + j * 16 + ur;
      const float4 bv = *(const float4*)&bias[gc0];
      const float v0 = acc[i][j][0] + bv.x, v1 = acc[i][j][1] + bv.y;
      const float v2 = acc[i][j][2] + bv.z, v3 = acc[i][j][3] + bv.w;
      if (OUT_BF16) {
        unsigned short p[4] = {f2b(v0), f2b(v1), f2b(v2), f2b(v3)};
        *(uint2*)((unsigned short*)Out + (size_t)gr * Nout + gc0) = *(const uint2*)p;
      } else {
        float4 o4; o4.x = v0; o4.y = v1; o4.z = v2; o4.w = v3;
        *(float4*)((float*)Out + (size_t)gr * Nout + gc0) = o4;
      }
    }
  }
}

// ---------------------------------------------------------------------------
// pass_a (split fp32): one block per (bh, split); 2 tiles of 128 tokens.
// Threads t<128 compute phi_k + stage v; 4 waves accumulate kv outer product;
// LDS cross-wave merge; float4 stores to per-(bh,split) kvP partials.
// ---------------------------------------------------------------------------
__global__ __launch_bounds__(256) void pass_a(
    const unsigned short* __restrict__ qkv, const float* __restrict__ rope,
    float* __restrict__ kvP) {
  __shared__ float sphi[128 * 65];               // 33,280 B (pad 65: no conflicts)
  __shared__ __align__(16) unsigned short sv[128 * 64];  // 16,384 B
  const int bh = blockIdx.x, b = bh / 12, h = bh % 12;
  const int sp = blockIdx.y;
  const int t = threadIdx.x;
  const int lane = t & 63, wave = t >> 6;
  const int dg = lane >> 2;   // d = dg*4 + i
  const int eg = lane & 3;    // e = eg*16 + j
  float acc[4][16] = {};
  float ks4[4] = {};

  const int tile0 = sp * TILES_PER_BLK;
  for (int tile = tile0; tile < tile0 + TILES_PER_BLK; tile++) {
    __syncthreads();
    if (t < 128) {
      const int n = tile * 128 + t;
      const size_t rowb = (size_t)(b * 4096 + n) * 2304;
      const unsigned short* kp = qkv + rowb + 768 + h * 64;
      float kk[64];
#pragma unroll
      for (int c = 0; c < 8; c++) {
        uint4 u = *(const uint4*)(kp + c * 8);
        unpack2(u.x, kk[c * 8 + 0], kk[c * 8 + 1]);
        unpack2(u.y, kk[c * 8 + 2], kk[c * 8 + 3]);
        unpack2(u.z, kk[c * 8 + 4], kk[c * 8 + 5]);
        unpack2(u.w, kk[c * 8 + 6], kk[c * 8 + 7]);
      }
      if (n > 0) {
        const float* rp = rope + (size_t)(n - 1) * 128;
#pragma unroll
        for (int c = 0; c < 8; c++) {
          float sn[8], cs[8];
          *(float4*)&sn[0] = *(const float4*)(rp + c * 8);
          *(float4*)&sn[4] = *(const float4*)(rp + c * 8 + 4);
          *(float4*)&cs[0] = *(const float4*)(rp + 64 + c * 8);
          *(float4*)&cs[4] = *(const float4*)(rp + 64 + c * 8 + 4);
#pragma unroll
          for (int i = 0; i < 4; i++) {
            float e = kk[c * 8 + 2 * i], o = kk[c * 8 + 2 * i + 1];
            kk[c * 8 + 2 * i] = e * cs[2 * i] - o * sn[2 * i];
            kk[c * 8 + 2 * i + 1] = o * cs[2 * i + 1] + e * sn[2 * i + 1];
          }
        }
      }
      float mx = kk[0];
#pragma unroll
      for (int i = 1; i < 64; i++) mx = fmaxf(mx, kk[i]);
      float s = 0.f;
#pragma unroll
      for (int i = 0; i < 64; i++) { float e = __expf(kk[i] - mx); kk[i] = e; s += e; }
      const float inv = 1.f / s;
#pragma unroll
      for (int d = 0; d < 64; d++) sphi[t * 65 + d] = kk[d] * inv;
      const unsigned short* vp = qkv + rowb + 1536 + h * 64;
#pragma unroll
      for (int c = 0; c < 8; c++)
        *(uint4*)&sv[t * 64 + c * 8] = *(const uint4*)(vp + c * 8);
    }
    __syncthreads();
    const int n0 = wave * 32;
    for (int nn = n0; nn < n0 + 32; nn++) {
      float p[4];
#pragma unroll
      for (int i = 0; i < 4; i++) p[i] = sphi[nn * 65 + dg * 4 + i];
#pragma unroll
      for (int i = 0; i < 4; i++) ks4[i] += p[i];
      float vv[16];
      {
        uint4 u0 = *(const uint4*)&sv[nn * 64 + eg * 16];
        uint4 u1 = *(const uint4*)&sv[nn * 64 + eg * 16 + 8];
        unpack2(u0.x, vv[0], vv[1]);   unpack2(u0.y, vv[2], vv[3]);
        unpack2(u0.z, vv[4], vv[5]);   unpack2(u0.w, vv[6], vv[7]);
        unpack2(u1.x, vv[8], vv[9]);   unpack2(u1.y, vv[10], vv[11]);
        unpack2(u1.z, vv[12], vv[13]); unpack2(u1.w, vv[14], vv[15]);
      }
#pragma unroll
      for (int i = 0; i < 4; i++)
#pragma unroll
        for (int j = 0; j < 16; j++)
          acc[i][j] += p[i] * vv[j];
    }
  }

  // ---- cross-wave merge via LDS (reuse sphi as scratch) ----
  __syncthreads();
  float* sred = sphi;
  float* o = kvP + ((size_t)bh * SPLIT_A + sp) * 4160;
#pragma unroll
  for (int half = 0; half < 2; half++) {
    if (wave != 0) {
      float* row = &sred[((wave - 1) * 64 + lane) * 33];
#pragma unroll
      for (int i = 0; i < 4; i++)
#pragma unroll
        for (int jj = 0; jj < 8; jj++) row[i * 8 + jj] = acc[i][half * 8 + jj];
    }
    __syncthreads();
    if (wave == 0) {
#pragma unroll
      for (int jj = 0; jj < 8; jj++) {
        float4 s4;
        float sv4[4];
#pragma unroll
        for (int i = 0; i < 4; i++) {
          float s = acc[i][half * 8 + jj];
#pragma unroll
          for (int w = 0; w < 3; w++) s += sred[(w * 64 + lane) * 33 + i * 8 + jj];
          sv4[i] = s;
        }
        s4.x = sv4[0]; s4.y = sv4[1]; s4.z = sv4[2]; s4.w = sv4[3];
        const int e = eg * 16 + half * 8 + jj;
        *(float4*)&o[e * 64 + dg * 4] = s4;
      }
    }
    __syncthreads();
  }
  // ---- ksum merge ----
  if (wave != 0) {
#pragma unroll
    for (int i = 0; i < 4; i++) sred[((wave - 1) * 64 + lane) * 5 + i] = ks4[i];
  }
  __syncthreads();
  if (wave == 0 && eg == 0) {
    float4 s4;
    float sv4[4];
#pragma unroll
    for (int i = 0; i < 4; i++) {
      float s = ks4[i];
#pragma unroll
      for (int w = 0; w < 3; w++) s += sred[(w * 64 + lane) * 5 + i];
      sv4[i] = s;
    }
    s4.x = sv4[0]; s4.y = sv4[1]; s4.z = sv4[2]; s4.w = sv4[3];
    *(float4*)&o[4096 + dg * 4] = s4;
  }
}

// ---------------------------------------------------------------------------
// reduce_kv: kvG[bh][r] = sum_{sp<SPLIT_A} kvP[bh][sp][r].
// ---------------------------------------------------------------------------
__global__ __launch_bounds__(256) void reduce_kv(
    const float* __restrict__ kvP, float* __restrict__ kvG) {
  const int i = blockIdx.x * 256 + threadIdx.x;
  if (i >= 96 * 4160) return;
  const int bh = i / 4160, r = i - bh * 4160;
  const float* p = kvP + (size_t)bh * SPLIT_A * 4160 + r;
  float s = 0.f;
#pragma unroll
  for (int sp = 0; sp < SPLIT_A; sp++) s += p[(size_t)sp * 4160];
  kvG[i] = s;
}

// ---------------------------------------------------------------------------
// pass_b (MFMA): block = (bh, 256-token tile). Each thread computes phi_q
// (fp32, rope+softmax) for one token + z; phi (normalized, bf16) -> swizzled
// LDS [256][64]; kv (bf16) -> swizzled LDS [64][64] (kvG is kv^T: o[e][d]).
// Then out(256x64) = P(256x64) x KVT(64x64)^T via 16x16x32 MFMA:
// wave wv owns tokens [wv*64, wv*64+64); mfma(kv_frag, p_frag) gives
// transposed D (col=token, row=e) -> packed 8B stores, zi from LDS.
// LDS slot swizzle: logical slot s (8 bf16) of row r stored at s^(r&7).
// ---------------------------------------------------------------------------
__global__ __launch_bounds__(256) void pass_b(
    const unsigned short* __restrict__ qkv, const float* __restrict__ rope,
    const float* __restrict__ kvG, unsigned short* __restrict__ attn) {
  __shared__ __align__(16) unsigned short sp_[256 * 64];  // 32,768 B phi bf16
  __shared__ __align__(16) unsigned short skv[64 * 64];   //  8,192 B kv  bf16
  __shared__ float szi[256];
  __shared__ float sks[64];
  const int bh = blockIdx.x, b = bh / 12, h = bh % 12;
  const int t = threadIdx.x;
  const float* kvb = kvG + (size_t)bh * 4160;

  // ---- stage kv (bf16, swizzled) + ksum ----
  {
    const int e = t >> 2, q = t & 3;              // row e, slot-pair q*2
    const float* src = kvb + e * 64 + q * 16;
    unsigned short tmp[16];
#pragma unroll
    for (int i = 0; i < 16; i++) tmp[i] = f2b(src[i]);
    *(uint4*)&skv[e * 64 + (((q * 2) ^ (e & 7)) * 8)] = *(uint4*)&tmp[0];
    *(uint4*)&skv[e * 64 + (((q * 2 + 1) ^ (e & 7)) * 8)] = *(uint4*)&tmp[8];
  }
  if (t < 64) sks[t] = kvb[4096 + t];
  __syncthreads();

  // ---- phi_q (fp32) for this thread's token ----
  const int n = blockIdx.y * 256 + t;
  const size_t rowb = (size_t)(b * 4096 + n) * 2304;
  const unsigned short* qp = qkv + rowb + h * 64;
  float ph[64];
#pragma unroll
  for (int c = 0; c < 8; c++) {
    uint4 u = *(const uint4*)(qp + c * 8);
    unpack2(u.x, ph[c * 8 + 0], ph[c * 8 + 1]);
    unpack2(u.y, ph[c * 8 + 2], ph[c * 8 + 3]);
    unpack2(u.z, ph[c * 8 + 4], ph[c * 8 + 5]);
    unpack2(u.w, ph[c * 8 + 6], ph[c * 8 + 7]);
  }
  if (n > 0) {
    const float* rp = rope + (size_t)(n - 1) * 128;
#pragma unroll
    for (int c = 0; c < 8; c++) {
      float sn[8], cs[8];
      *(float4*)&sn[0] = *(const float4*)(rp + c * 8);
      *(float4*)&sn[4] = *(const float4*)(rp + c * 8 + 4);
      *(float4*)&cs[0] = *(const float4*)(rp + 64 + c * 8);
      *(float4*)&cs[4] = *(const float4*)(rp + 64 + c * 8 + 4);
#pragma unroll
      for (int i = 0; i < 4; i++) {
        float e = ph[c * 8 + 2 * i], o = ph[c * 8 + 2 * i + 1];
        ph[c * 8 + 2 * i] = e * cs[2 * i] - o * sn[2 * i];
        ph[c * 8 + 2 * i + 1] = o * cs[2 * i + 1] + e * sn[2 * i + 1];
      }
    }
  }
  float mx = ph[0];
#pragma unroll
  for (int i = 1; i < 64; i++) mx = fmaxf(mx, ph[i]);
  float s = 0.f;
#pragma unroll
  for (int i = 0; i < 64; i++) { float e = __expf(ph[i] - mx); ph[i] = e; s += e; }
  const float inv = 1.f / s;
  float z = 0.f;
#pragma unroll
  for (int i = 0; i < 64; i++) { ph[i] *= inv; z += ph[i] * sks[i]; }
  szi[t] = 1.f / (z + 1e-5f);

  // ---- phi -> bf16 swizzled LDS row t ----
#pragma unroll
  for (int sl = 0; sl < 8; sl += 2) {
    unsigned short tmp[16];
#pragma unroll
    for (int i = 0; i < 16; i++) tmp[i] = f2b(ph[sl * 8 + i]);
    *(uint4*)&sp_[t * 64 + ((sl ^ (t & 7)) * 8)] = *(uint4*)&tmp[0];
    *(uint4*)&sp_[t * 64 + (((sl + 1) ^ (t & 7)) * 8)] = *(uint4*)&tmp[8];
  }
  __syncthreads();

  // ---- MFMA: wave wv -> tokens [wv*64, wv*64+64), all 64 e ----
  const int lane = t & 63, wv = t >> 6;
  const int fr = lane & 15, fq = lane >> 4;
  floatx4 acc[4][4] = {};
#pragma unroll
  for (int kk = 0; kk < 2; kk++) {
    short8 kvf[4], pf[4];
#pragma unroll
    for (int j = 0; j < 4; j++) {
      const int e = j * 16 + fr;
      kvf[j] = *(const short8*)&skv[e * 64 + (((kk * 4 + fq) ^ (e & 7)) * 8)];
    }
#pragma unroll
    for (int i = 0; i < 4; i++) {
      const int tok = wv * 64 + i * 16 + fr;
      pf[i] = *(const short8*)&sp_[tok * 64 + (((kk * 4 + fq) ^ (tok & 7)) * 8)];
    }
#pragma unroll
    for (int i = 0; i < 4; i++)
#pragma unroll
      for (int j = 0; j < 4; j++)
        acc[i][j] = __builtin_amdgcn_mfma_f32_16x16x32_bf16(kvf[j], pf[i], acc[i][j], 0, 0, 0);
  }

  // ---- epilogue: D col = token (lane&15), D row = e quad (fq*4+r) ----
#pragma unroll
  for (int i = 0; i < 4; i++) {
    const int tokl = wv * 64 + i * 16 + fr;
    const float zi = szi[tokl];
    unsigned short* orow =
        attn + (size_t)(b * 4096 + blockIdx.y * 256 + tokl) * 768 + h * 64;
#pragma unroll
    for (int j = 0; j < 4; j++) {
      const int e0 = j * 16 + fq * 4;
      unsigned short pk[4] = {f2b(acc[i][j][0] * zi), f2b(acc[i][j][1] * zi),
                              f2b(acc[i][j][2] * zi), f2b(acc[i][j][3] * zi)};
      *(uint2*)(orow + e0) = *(const uint2*)pk;
    }
  }
}

// ---------------------------------------------------------------------------
// LayerNorm over C=768, in-place on bf16 buffer; gamma/beta fp32.
// ---------------------------------------------------------------------------
__global__ __launch_bounds__(256) void ln_kernel(
    unsigned short* __restrict__ buf, const float* __restrict__ g,
    const float* __restrict__ be) {
  const int row = blockIdx.x;
  const int t = threadIdx.x;
  unsigned short* p = buf + (size_t)row * 768;
  const float x0 = b2f(p[t]), x1 = b2f(p[t + 256]), x2 = b2f(p[t + 512]);
  float s = x0 + x1 + x2;
  float ss = x0 * x0 + x1 * x1 + x2 * x2;
#pragma unroll
  for (int m = 1; m < 64; m <<= 1) { s += __shfl_xor(s, m); ss += __shfl_xor(ss, m); }
  __shared__ float red[8];
  const int wave = t >> 6, lane = t & 63;
  if (lane == 0) { red[wave] = s; red[4 + wave] = ss; }
  __syncthreads();
  s = red[0] + red[1] + red[2] + red[3];
  ss = red[4] + red[5] + red[6] + red[7];
  const float mean = s * (1.f / 768.f);
  const float var = ss * (1.f / 768.f) - mean * mean;
  const float rsq = rsqrtf(var + 1e-5f);
  p[t] = f2b((x0 - mean) * rsq * g[t] + be[t]);
  p[t + 256] = f2b((x1 - mean) * rsq * g[t + 256] + be[t + 256]);
  p[t + 512] = f2b((x2 - mean) * rsq * g[t + 512] + be[t + 512]);
}

// ---------------------------------------------------------------------------
extern "C" void kernel_launch(void* const* d_in, const int* in_sizes, int n_in,
                              void* d_out, int out_size, void* d_ws, size_t ws_size,
                              hipStream_t stream) {
  (void)in_sizes; (void)n_in; (void)out_size; (void)ws_size;
  const float* x      = (const float*)d_in[0];
  const float* rope   = (const float*)d_in[1];
  const float* qkv_w  = (const float*)d_in[2];
  const float* q_bias = (const float*)d_in[3];
  const float* v_bias = (const float*)d_in[4];
  const float* norm_g = (const float*)d_in[5];
  const float* norm_b = (const float*)d_in[6];
  const float* proj_w = (const float*)d_in[7];
  const float* proj_b = (const float*)d_in[8];

  char* ws = (char*)d_ws;
  unsigned short* qkv  = (unsigned short*)ws;                // 150,994,944 B
  unsigned short* attn = (unsigned short*)(ws + 150994944);  //  50,331,648 B
  unsigned short* xbf  = attn;  // aliased: x_bf16 dead before attn is written
  float* kvP   = (float*)(ws + 150994944);  // aliased: partials dead before attn
  float* kvG   = (float*)(ws + 201326592);                   //   1,597,440 B
  float* qkvb  = (float*)(ws + 202924032);
  float* projb = (float*)(ws + 202933248);
  unsigned short* wbf  = (unsigned short*)(ws + 202936320);  //   3,538,944 B
  unsigned short* pwbf = (unsigned short*)(ws + 206475264);  //   1,179,648 B

  f32_to_bf16<<<dim3(12288), dim3(256), 0, stream>>>(x, xbf, 25165824);
  prep<<<dim3(1161), dim3(256), 0, stream>>>(qkv_w, proj_w, q_bias, v_bias,
                                             proj_b, wbf, pwbf, qkvb, projb);
  // qkv = x @ qkv_w^T + qkv_bias (M=32768, K=768, Nout=2304), bf16 out
  gemm_bt<1><<<dim3(4608), dim3(256), 0, stream>>>(xbf, wbf, qkvb, qkv, 32768, 768, 2304, 18);
  // NOTE: xbf (== kvP region) is dead from here on.
  pass_a<<<dim3(96, SPLIT_A), dim3(256), 0, stream>>>(qkv, rope, kvP);
  reduce_kv<<<dim3(1560), dim3(256), 0, stream>>>(kvP, kvG);
  // attn = phi_q @ kv / (z + eps) (MFMA, bf16); overwrites kvP region
  pass_b<<<dim3(96, 16), dim3(256), 0, stream>>>(qkv, rope, kvG, attn);
  ln_kernel<<<dim3(32768), dim3(256), 0, stream>>>(attn, norm_g, norm_b);
  // out = ln @ proj_w^T + proj_b (M=32768, K=768, Nout=768) -> d_out fp32
  gemm_bt<0><<<dim3(1536), dim3(256), 0, stream>>>(attn, pwbf, projb, d_out, 32768, 768, 768, 6);
}

// Round 6
// 583.288 us; speedup vs baseline: 1.5010x; 1.1125x over previous
//
#include <hip/hip_runtime.h>
#include <stdint.h>

// ---------------------------------------------------------------------------
// EvaLinearAttention on MI355X (gfx950).
// B=8, N=4096, C=768, H=12, D=64, npt=1. I/O fp32; GEMMs bf16 MFMA.
// R1: pass_a 16-way token split (310us -> off top-5). 875 -> 666us.
// R2: XCD-chunked swizzle on GEMMs: FETCH 250->124MB, 190->180us.
// R3: BK=64 + LDS swizzle: conflicts->0 but occupancy 32->22%, 180->187.
// R4: BK=32 + transposed packed epilogue + MFMA pass_b: pass_b saved ~55us
//     but epilogue pushed VGPR 84->96, occupancy 32->22%, FETCH 124->155MB,
//     QKV gemm 180->238. Net flat.
// R5 (this): restore EXACT R2 gemm_bt (mfma(af,bfr), scalar stores, VGPR 84,
//     measured 180us in this pipeline); keep R4's MFMA pass_b + prep.
// ---------------------------------------------------------------------------

typedef __attribute__((ext_vector_type(8))) short short8;
typedef __attribute__((ext_vector_type(4))) float floatx4;

#define SPLIT_A 16
#define TILES_PER_BLK (32 / SPLIT_A)

__device__ __forceinline__ float b2f(unsigned short u) {
  union { unsigned int i; float f; } v; v.i = ((unsigned int)u) << 16; return v.f;
}
__device__ __forceinline__ unsigned short f2b(float f) {
  union { float f; unsigned int i; } v; v.f = f;
  unsigned int i = v.i;
  unsigned int r = (i + 0x7FFFu + ((i >> 16) & 1u)) >> 16;  // RNE
  return (unsigned short)r;
}
__device__ __forceinline__ void unpack2(unsigned int u, float& a, float& b) {
  union { unsigned int i; float f; } x, y;
  x.i = u << 16; y.i = u & 0xFFFF0000u;
  a = x.f; b = y.f;
}

__device__ __forceinline__ void stage16(const void* g, void* l) {
#if defined(__has_builtin) && __has_builtin(__builtin_amdgcn_global_load_lds)
  __builtin_amdgcn_global_load_lds(
      (const __attribute__((address_space(1))) unsigned int*)g,
      (__attribute__((address_space(3))) unsigned int*)l, 16, 0, 0);
#else
  *(uint4*)l = *(const uint4*)g;
#endif
}

// ---------------------------------------------------------------------------
__global__ __launch_bounds__(256) void f32_to_bf16(
    const float* __restrict__ in, unsigned short* __restrict__ out, int n) {
  const int i = (blockIdx.x * 256 + threadIdx.x) * 8;
  if (i + 7 < n) {
    float4 a = *(const float4*)(in + i);
    float4 b = *(const float4*)(in + i + 4);
    unsigned short tmp[8] = {f2b(a.x), f2b(a.y), f2b(a.z), f2b(a.w),
                             f2b(b.x), f2b(b.y), f2b(b.z), f2b(b.w)};
    *(uint4*)(out + i) = *(uint4*)tmp;
  }
}

// ---------------------------------------------------------------------------
// prep: convert qkv_w and proj_w to bf16, build fused qkv bias + proj bias.
// ---------------------------------------------------------------------------
__global__ __launch_bounds__(256) void prep(
    const float* __restrict__ w, const float* __restrict__ pw,
    const float* __restrict__ qb, const float* __restrict__ vb,
    const float* __restrict__ pb,
    unsigned short* __restrict__ wbf, unsigned short* __restrict__ pwbf,
    float* __restrict__ qkvb, float* __restrict__ projb) {
  const int blk = blockIdx.x, t = threadIdx.x;
  if (blk < 1152) {
    const float* src = (blk < 864) ? w : pw;
    unsigned short* dst = (blk < 864) ? wbf : pwbf;
    const int i = ((blk < 864 ? blk : blk - 864) * 256 + t) * 8;
    float4 a = *(const float4*)(src + i);
    float4 b = *(const float4*)(src + i + 4);
    unsigned short tmp[8] = {f2b(a.x), f2b(a.y), f2b(a.z), f2b(a.w),
                             f2b(b.x), f2b(b.y), f2b(b.z), f2b(b.w)};
    *(uint4*)(dst + i) = *(uint4*)tmp;
  } else {
    const int i = (blk - 1152) * 256 + t;
    if (i < 2304) qkvb[i] = (i < 768) ? qb[i] : (i >= 1536 ? vb[i - 1536] : 0.f);
    if (i < 768) projb[i] = pb[i];
  }
}

// ---------------------------------------------------------------------------
// bf16 GEMM, B^T: Out[M,Nout] = A[M,K] * W[Nout,K]^T + bias. (m97 pattern)
// EXACT R2 form (measured 179-180us in this pipeline): BK=32, 16KB LDS,
// VGPR 84, mfma(af, bfr), scalar C-stores. 1D grid, XCD-chunked swizzle
// (gridDim.x % 8 == 0), bn innermost for A-panel reuse / W L2-residency.
// ---------------------------------------------------------------------------
template <int OUT_BF16>
__global__ __launch_bounds__(256) void gemm_bt(
    const unsigned short* __restrict__ A, const unsigned short* __restrict__ W,
    const float* __restrict__ bias, void* __restrict__ Out,
    int M, int K, int Nout, int nbn) {
  __shared__ __align__(16) unsigned short sA[128 * 32];
  __shared__ __align__(16) unsigned short sB[128 * 32];
  const int nwg = gridDim.x;
  const int orig = blockIdx.x;
  const int wg = (orig & 7) * (nwg >> 3) + (orig >> 3);  // bijective: nwg%8==0
  const int bm = wg / nbn;
  const int bn = wg - bm * nbn;
  const int t = threadIdx.x;
  const int lane = t & 63, wave = t >> 6;
  const int wm = (wave >> 1) * 64, wn = (wave & 1) * 64;
  const int lr = t >> 2;
  const int lc = (t & 3) * 8;
  const size_t baseA = (size_t)(bm * 128 + lr) * K + lc;
  const size_t baseB = (size_t)(bn * 128 + lr) * K + lc;
  floatx4 acc[4][4] = {};

  const int mr = lane & 15, kq = (lane >> 4) * 8;
  for (int k0 = 0; k0 < K; k0 += 32) {
    stage16(A + baseA + k0, &sA[t * 8]);
    stage16(A + baseA + (size_t)64 * K + k0, &sA[2048 + t * 8]);
    stage16(W + baseB + k0, &sB[t * 8]);
    stage16(W + baseB + (size_t)64 * K + k0, &sB[2048 + t * 8]);
    __syncthreads();
    short8 af[4], bfr[4];
#pragma unroll
    for (int i = 0; i < 4; i++) af[i] = *(const short8*)&sA[(wm + i * 16 + mr) * 32 + kq];
#pragma unroll
    for (int j = 0; j < 4; j++) bfr[j] = *(const short8*)&sB[(wn + j * 16 + mr) * 32 + kq];
#pragma unroll
    for (int i = 0; i < 4; i++)
#pragma unroll
      for (int j = 0; j < 4; j++)
        acc[i][j] = __builtin_amdgcn_mfma_f32_16x16x32_bf16(af[i], bfr[j], acc[i][j], 0, 0, 0);
    __syncthreads();
  }

  const int mr4 = (lane >> 4) * 4, nc = lane & 15;
#pragma unroll
  for (int j = 0; j < 4; j++) {
    const int gc = bn * 128 + wn + j * 16 + nc;
    const float bv = bias[gc];
#pragma unroll
    for (int i = 0; i < 4; i++) {
      const int gr0 = bm * 128 + wm + i * 16 + mr4;
#pragma unroll
      for (int r = 0; r < 4; r++) {
        float v = acc[i][j][r] + bv;
        if (OUT_BF16)
          ((unsigned short*)Out)[(size_t)(gr0 + r) * Nout + gc] = f2b(v);
        else
          ((float*)Out)[(size_t)(gr0 + r) * Nout + gc] = v;
      }
    }
  }
}

// ---------------------------------------------------------------------------
// pass_a (split fp32): one block per (bh, split); 2 tiles of 128 tokens.
// Threads t<128 compute phi_k + stage v; 4 waves accumulate kv outer product;
// LDS cross-wave merge; float4 stores to per-(bh,split) kvP partials.
// ---------------------------------------------------------------------------
__global__ __launch_bounds__(256) void pass_a(
    const unsigned short* __restrict__ qkv, const float* __restrict__ rope,
    float* __restrict__ kvP) {
  __shared__ float sphi[128 * 65];               // 33,280 B (pad 65: no conflicts)
  __shared__ __align__(16) unsigned short sv[128 * 64];  // 16,384 B
  const int bh = blockIdx.x, b = bh / 12, h = bh % 12;
  const int sp = blockIdx.y;
  const int t = threadIdx.x;
  const int lane = t & 63, wave = t >> 6;
  const int dg = lane >> 2;   // d = dg*4 + i
  const int eg = lane & 3;    // e = eg*16 + j
  float acc[4][16] = {};
  float ks4[4] = {};

  const int tile0 = sp * TILES_PER_BLK;
  for (int tile = tile0; tile < tile0 + TILES_PER_BLK; tile++) {
    __syncthreads();
    if (t < 128) {
      const int n = tile * 128 + t;
      const size_t rowb = (size_t)(b * 4096 + n) * 2304;
      const unsigned short* kp = qkv + rowb + 768 + h * 64;
      float kk[64];
#pragma unroll
      for (int c = 0; c < 8; c++) {
        uint4 u = *(const uint4*)(kp + c * 8);
        unpack2(u.x, kk[c * 8 + 0], kk[c * 8 + 1]);
        unpack2(u.y, kk[c * 8 + 2], kk[c * 8 + 3]);
        unpack2(u.z, kk[c * 8 + 4], kk[c * 8 + 5]);
        unpack2(u.w, kk[c * 8 + 6], kk[c * 8 + 7]);
      }
      if (n > 0) {
        const float* rp = rope + (size_t)(n - 1) * 128;
#pragma unroll
        for (int c = 0; c < 8; c++) {
          float sn[8], cs[8];
          *(float4*)&sn[0] = *(const float4*)(rp + c * 8);
          *(float4*)&sn[4] = *(const float4*)(rp + c * 8 + 4);
          *(float4*)&cs[0] = *(const float4*)(rp + 64 + c * 8);
          *(float4*)&cs[4] = *(const float4*)(rp + 64 + c * 8 + 4);
#pragma unroll
          for (int i = 0; i < 4; i++) {
            float e = kk[c * 8 + 2 * i], o = kk[c * 8 + 2 * i + 1];
            kk[c * 8 + 2 * i] = e * cs[2 * i] - o * sn[2 * i];
            kk[c * 8 + 2 * i + 1] = o * cs[2 * i + 1] + e * sn[2 * i + 1];
          }
        }
      }
      float mx = kk[0];
#pragma unroll
      for (int i = 1; i < 64; i++) mx = fmaxf(mx, kk[i]);
      float s = 0.f;
#pragma unroll
      for (int i = 0; i < 64; i++) { float e = __expf(kk[i] - mx); kk[i] = e; s += e; }
      const float inv = 1.f / s;
#pragma unroll
      for (int d = 0; d < 64; d++) sphi[t * 65 + d] = kk[d] * inv;
      const unsigned short* vp = qkv + rowb + 1536 + h * 64;
#pragma unroll
      for (int c = 0; c < 8; c++)
        *(uint4*)&sv[t * 64 + c * 8] = *(const uint4*)(vp + c * 8);
    }
    __syncthreads();
    const int n0 = wave * 32;
    for (int nn = n0; nn < n0 + 32; nn++) {
      float p[4];
#pragma unroll
      for (int i = 0; i < 4; i++) p[i] = sphi[nn * 65 + dg * 4 + i];
#pragma unroll
      for (int i = 0; i < 4; i++) ks4[i] += p[i];
      float vv[16];
      {
        uint4 u0 = *(const uint4*)&sv[nn * 64 + eg * 16];
        uint4 u1 = *(const uint4*)&sv[nn * 64 + eg * 16 + 8];
        unpack2(u0.x, vv[0], vv[1]);   unpack2(u0.y, vv[2], vv[3]);
        unpack2(u0.z, vv[4], vv[5]);   unpack2(u0.w, vv[6], vv[7]);
        unpack2(u1.x, vv[8], vv[9]);   unpack2(u1.y, vv[10], vv[11]);
        unpack2(u1.z, vv[12], vv[13]); unpack2(u1.w, vv[14], vv[15]);
      }
#pragma unroll
      for (int i = 0; i < 4; i++)
#pragma unroll
        for (int j = 0; j < 16; j++)
          acc[i][j] += p[i] * vv[j];
    }
  }

  // ---- cross-wave merge via LDS (reuse sphi as scratch) ----
  __syncthreads();
  float* sred = sphi;
  float* o = kvP + ((size_t)bh * SPLIT_A + sp) * 4160;
#pragma unroll
  for (int half = 0; half < 2; half++) {
    if (wave != 0) {
      float* row = &sred[((wave - 1) * 64 + lane) * 33];
#pragma unroll
      for (int i = 0; i < 4; i++)
#pragma unroll
        for (int jj = 0; jj < 8; jj++) row[i * 8 + jj] = acc[i][half * 8 + jj];
    }
    __syncthreads();
    if (wave == 0) {
#pragma unroll
      for (int jj = 0; jj < 8; jj++) {
        float4 s4;
        float sv4[4];
#pragma unroll
        for (int i = 0; i < 4; i++) {
          float s = acc[i][half * 8 + jj];
#pragma unroll
          for (int w = 0; w < 3; w++) s += sred[(w * 64 + lane) * 33 + i * 8 + jj];
          sv4[i] = s;
        }
        s4.x = sv4[0]; s4.y = sv4[1]; s4.z = sv4[2]; s4.w = sv4[3];
        const int e = eg * 16 + half * 8 + jj;
        *(float4*)&o[e * 64 + dg * 4] = s4;
      }
    }
    __syncthreads();
  }
  // ---- ksum merge ----
  if (wave != 0) {
#pragma unroll
    for (int i = 0; i < 4; i++) sred[((wave - 1) * 64 + lane) * 5 + i] = ks4[i];
  }
  __syncthreads();
  if (wave == 0 && eg == 0) {
    float4 s4;
    float sv4[4];
#pragma unroll
    for (int i = 0; i < 4; i++) {
      float s = ks4[i];
#pragma unroll
      for (int w = 0; w < 3; w++) s += sred[(w * 64 + lane) * 5 + i];
      sv4[i] = s;
    }
    s4.x = sv4[0]; s4.y = sv4[1]; s4.z = sv4[2]; s4.w = sv4[3];
    *(float4*)&o[4096 + dg * 4] = s4;
  }
}

// ---------------------------------------------------------------------------
// reduce_kv: kvG[bh][r] = sum_{sp<SPLIT_A} kvP[bh][sp][r].
// ---------------------------------------------------------------------------
__global__ __launch_bounds__(256) void reduce_kv(
    const float* __restrict__ kvP, float* __restrict__ kvG) {
  const int i = blockIdx.x * 256 + threadIdx.x;
  if (i >= 96 * 4160) return;
  const int bh = i / 4160, r = i - bh * 4160;
  const float* p = kvP + (size_t)bh * SPLIT_A * 4160 + r;
  float s = 0.f;
#pragma unroll
  for (int sp = 0; sp < SPLIT_A; sp++) s += p[(size_t)sp * 4160];
  kvG[i] = s;
}

// ---------------------------------------------------------------------------
// pass_b (MFMA): block = (bh, 256-token tile). Each thread computes phi_q
// (fp32, rope+softmax) for one token + z; phi (normalized, bf16) -> swizzled
// LDS [256][64]; kv (bf16) -> swizzled LDS [64][64] (kvG is kv^T: o[e][d]).
// Then out(256x64) = P(256x64) x KVT(64x64)^T via 16x16x32 MFMA:
// wave wv owns tokens [wv*64, wv*64+64); mfma(kv_frag, p_frag) gives
// transposed D (col=token, row=e) -> packed 8B stores, zi from LDS.
// LDS slot swizzle: logical slot s (8 bf16) of row r stored at s^(r&7).
// ---------------------------------------------------------------------------
__global__ __launch_bounds__(256) void pass_b(
    const unsigned short* __restrict__ qkv, const float* __restrict__ rope,
    const float* __restrict__ kvG, unsigned short* __restrict__ attn) {
  __shared__ __align__(16) unsigned short sp_[256 * 64];  // 32,768 B phi bf16
  __shared__ __align__(16) unsigned short skv[64 * 64];   //  8,192 B kv  bf16
  __shared__ float szi[256];
  __shared__ float sks[64];
  const int bh = blockIdx.x, b = bh / 12, h = bh % 12;
  const int t = threadIdx.x;
  const float* kvb = kvG + (size_t)bh * 4160;

  // ---- stage kv (bf16, swizzled) + ksum ----
  {
    const int e = t >> 2, q = t & 3;              // row e, slot-pair q*2
    const float* src = kvb + e * 64 + q * 16;
    unsigned short tmp[16];
#pragma unroll
    for (int i = 0; i < 16; i++) tmp[i] = f2b(src[i]);
    *(uint4*)&skv[e * 64 + (((q * 2) ^ (e & 7)) * 8)] = *(uint4*)&tmp[0];
    *(uint4*)&skv[e * 64 + (((q * 2 + 1) ^ (e & 7)) * 8)] = *(uint4*)&tmp[8];
  }
  if (t < 64) sks[t] = kvb[4096 + t];
  __syncthreads();

  // ---- phi_q (fp32) for this thread's token ----
  const int n = blockIdx.y * 256 + t;
  const size_t rowb = (size_t)(b * 4096 + n) * 2304;
  const unsigned short* qp = qkv + rowb + h * 64;
  float ph[64];
#pragma unroll
  for (int c = 0; c < 8; c++) {
    uint4 u = *(const uint4*)(qp + c * 8);
    unpack2(u.x, ph[c * 8 + 0], ph[c * 8 + 1]);
    unpack2(u.y, ph[c * 8 + 2], ph[c * 8 + 3]);
    unpack2(u.z, ph[c * 8 + 4], ph[c * 8 + 5]);
    unpack2(u.w, ph[c * 8 + 6], ph[c * 8 + 7]);
  }
  if (n > 0) {
    const float* rp = rope + (size_t)(n - 1) * 128;
#pragma unroll
    for (int c = 0; c < 8; c++) {
      float sn[8], cs[8];
      *(float4*)&sn[0] = *(const float4*)(rp + c * 8);
      *(float4*)&sn[4] = *(const float4*)(rp + c * 8 + 4);
      *(float4*)&cs[0] = *(const float4*)(rp + 64 + c * 8);
      *(float4*)&cs[4] = *(const float4*)(rp + 64 + c * 8 + 4);
#pragma unroll
      for (int i = 0; i < 4; i++) {
        float e = ph[c * 8 + 2 * i], o = ph[c * 8 + 2 * i + 1];
        ph[c * 8 + 2 * i] = e * cs[2 * i] - o * sn[2 * i];
        ph[c * 8 + 2 * i + 1] = o * cs[2 * i + 1] + e * sn[2 * i + 1];
      }
    }
  }
  float mx = ph[0];
#pragma unroll
  for (int i = 1; i < 64; i++) mx = fmaxf(mx, ph[i]);
  float s = 0.f;
#pragma unroll
  for (int i = 0; i < 64; i++) { float e = __expf(ph[i] - mx); ph[i] = e; s += e; }
  const float inv = 1.f / s;
  float z = 0.f;
#pragma unroll
  for (int i = 0; i < 64; i++) { ph[i] *= inv; z += ph[i] * sks[i]; }
  szi[t] = 1.f / (z + 1e-5f);

  // ---- phi -> bf16 swizzled LDS row t ----
#pragma unroll
  for (int sl = 0; sl < 8; sl += 2) {
    unsigned short tmp[16];
#pragma unroll
    for (int i = 0; i < 16; i++) tmp[i] = f2b(ph[sl * 8 + i]);
    *(uint4*)&sp_[t * 64 + ((sl ^ (t & 7)) * 8)] = *(uint4*)&tmp[0];
    *(uint4*)&sp_[t * 64 + (((sl + 1) ^ (t & 7)) * 8)] = *(uint4*)&tmp[8];
  }
  __syncthreads();

  // ---- MFMA: wave wv -> tokens [wv*64, wv*64+64), all 64 e ----
  const int lane = t & 63, wv = t >> 6;
  const int fr = lane & 15, fq = lane >> 4;
  floatx4 acc[4][4] = {};
#pragma unroll
  for (int kk = 0; kk < 2; kk++) {
    short8 kvf[4], pf[4];
#pragma unroll
    for (int j = 0; j < 4; j++) {
      const int e = j * 16 + fr;
      kvf[j] = *(const short8*)&skv[e * 64 + (((kk * 4 + fq) ^ (e & 7)) * 8)];
    }
#pragma unroll
    for (int i = 0; i < 4; i++) {
      const int tok = wv * 64 + i * 16 + fr;
      pf[i] = *(const short8*)&sp_[tok * 64 + (((kk * 4 + fq) ^ (tok & 7)) * 8)];
    }
#pragma unroll
    for (int i = 0; i < 4; i++)
#pragma unroll
      for (int j = 0; j < 4; j++)
        acc[i][j] = __builtin_amdgcn_mfma_f32_16x16x32_bf16(kvf[j], pf[i], acc[i][j], 0, 0, 0);
  }

  // ---- epilogue: D col = token (lane&15), D row = e quad (fq*4+r) ----
#pragma unroll
  for (int i = 0; i < 4; i++) {
    const int tokl = wv * 64 + i * 16 + fr;
    const float zi = szi[tokl];
    unsigned short* orow =
        attn + (size_t)(b * 4096 + blockIdx.y * 256 + tokl) * 768 + h * 64;
#pragma unroll
    for (int j = 0; j < 4; j++) {
      const int e0 = j * 16 + fq * 4;
      unsigned short pk[4] = {f2b(acc[i][j][0] * zi), f2b(acc[i][j][1] * zi),
                              f2b(acc[i][j][2] * zi), f2b(acc[i][j][3] * zi)};
      *(uint2*)(orow + e0) = *(const uint2*)pk;
    }
  }
}

// ---------------------------------------------------------------------------
// LayerNorm over C=768, in-place on bf16 buffer; gamma/beta fp32.
// ---------------------------------------------------------------------------
__global__ __launch_bounds__(256) void ln_kernel(
    unsigned short* __restrict__ buf, const float* __restrict__ g,
    const float* __restrict__ be) {
  const int row = blockIdx.x;
  const int t = threadIdx.x;
  unsigned short* p = buf + (size_t)row * 768;
  const float x0 = b2f(p[t]), x1 = b2f(p[t + 256]), x2 = b2f(p[t + 512]);
  float s = x0 + x1 + x2;
  float ss = x0 * x0 + x1 * x1 + x2 * x2;
#pragma unroll
  for (int m = 1; m < 64; m <<= 1) { s += __shfl_xor(s, m); ss += __shfl_xor(ss, m); }
  __shared__ float red[8];
  const int wave = t >> 6, lane = t & 63;
  if (lane == 0) { red[wave] = s; red[4 + wave] = ss; }
  __syncthreads();
  s = red[0] + red[1] + red[2] + red[3];
  ss = red[4] + red[5] + red[6] + red[7];
  const float mean = s * (1.f / 768.f);
  const float var = ss * (1.f / 768.f) - mean * mean;
  const float rsq = rsqrtf(var + 1e-5f);
  p[t] = f2b((x0 - mean) * rsq * g[t] + be[t]);
  p[t + 256] = f2b((x1 - mean) * rsq * g[t + 256] + be[t + 256]);
  p[t + 512] = f2b((x2 - mean) * rsq * g[t + 512] + be[t + 512]);
}

// ---------------------------------------------------------------------------
extern "C" void kernel_launch(void* const* d_in, const int* in_sizes, int n_in,
                              void* d_out, int out_size, void* d_ws, size_t ws_size,
                              hipStream_t stream) {
  (void)in_sizes; (void)n_in; (void)out_size; (void)ws_size;
  const float* x      = (const float*)d_in[0];
  const float* rope   = (const float*)d_in[1];
  const float* qkv_w  = (const float*)d_in[2];
  const float* q_bias = (const float*)d_in[3];
  const float* v_bias = (const float*)d_in[4];
  const float* norm_g = (const float*)d_in[5];
  const float* norm_b = (const float*)d_in[6];
  const float* proj_w = (const float*)d_in[7];
  const float* proj_b = (const float*)d_in[8];

  char* ws = (char*)d_ws;
  unsigned short* qkv  = (unsigned short*)ws;                // 150,994,944 B
  unsigned short* attn = (unsigned short*)(ws + 150994944);  //  50,331,648 B
  unsigned short* xbf  = attn;  // aliased: x_bf16 dead before attn is written
  float* kvP   = (float*)(ws + 150994944);  // aliased: partials dead before attn
  float* kvG   = (float*)(ws + 201326592);                   //   1,597,440 B
  float* qkvb  = (float*)(ws + 202924032);
  float* projb = (float*)(ws + 202933248);
  unsigned short* wbf  = (unsigned short*)(ws + 202936320);  //   3,538,944 B
  unsigned short* pwbf = (unsigned short*)(ws + 206475264);  //   1,179,648 B

  f32_to_bf16<<<dim3(12288), dim3(256), 0, stream>>>(x, xbf, 25165824);
  prep<<<dim3(1161), dim3(256), 0, stream>>>(qkv_w, proj_w, q_bias, v_bias,
                                             proj_b, wbf, pwbf, qkvb, projb);
  // qkv = x @ qkv_w^T + qkv_bias (M=32768, K=768, Nout=2304), bf16 out
  gemm_bt<1><<<dim3(4608), dim3(256), 0, stream>>>(xbf, wbf, qkvb, qkv, 32768, 768, 2304, 18);
  // NOTE: xbf (== kvP region) is dead from here on.
  pass_a<<<dim3(96, SPLIT_A), dim3(256), 0, stream>>>(qkv, rope, kvP);
  reduce_kv<<<dim3(1560), dim3(256), 0, stream>>>(kvP, kvG);
  // attn = phi_q @ kv / (z + eps) (MFMA, bf16); overwrites kvP region
  pass_b<<<dim3(96, 16), dim3(256), 0, stream>>>(qkv, rope, kvG, attn);
  ln_kernel<<<dim3(32768), dim3(256), 0, stream>>>(attn, norm_g, norm_b);
  // out = ln @ proj_w^T + proj_b (M=32768, K=768, Nout=768) -> d_out fp32
  gemm_bt<0><<<dim3(1536), dim3(256), 0, stream>>>(attn, pwbf, projb, d_out, 32768, 768, 768, 6);
}